// Round 4
// baseline (303.823 us; speedup 1.0000x reference)
//
#include <hip/hip_runtime.h>
#include <hip/hip_bf16.h>
#include <cstdint>
#include <cstddef>

// ---------------------------------------------------------------------------
// LlamaAttention forward: out = Attn(RoPE(x@wq), RoPE(x@wk), x@wv) @ wo
// B=2 T=2048 C=2048 NH=32 NKV=8 D=64, causal, GQA rep=4, scale=1/8.
// R4: attn occupancy fix — split-KV across wave pairs (8192 waves, was 4096),
// LDS merge of online-softmax partials; all shfl_xor replaced with
// v_permlane32_swap_b32 (VALU, ~4cy vs ds_bpermute ~60+cy); Q pre-scaled by
// 0.125*log2(e) inside rope_kernel.
// ---------------------------------------------------------------------------

using bf16 = __hip_bfloat16;
using f32x4  = __attribute__((ext_vector_type(4))) float;
using f32x16 = __attribute__((ext_vector_type(16))) float;
using short8 = __attribute__((ext_vector_type(8))) short;
using u32x4  = __attribute__((ext_vector_type(4))) unsigned int;

typedef __attribute__((address_space(1))) const void* gp1_t;
typedef __attribute__((address_space(3))) void*       lp3_t;

#define GLOAD_LDS16(g, l)                                                     \
  __builtin_amdgcn_global_load_lds((gp1_t)(const void*)(g), (lp3_t)(void*)(l), 16, 0, 0)

#define MFMA32(a, b, c) __builtin_amdgcn_mfma_f32_32x32x16_bf16(a, b, c, 0, 0, 0)

static constexpr int Bd  = 2;
static constexpr int Td  = 2048;
static constexpr int Cd  = 2048;
static constexpr int NH  = 32;
static constexpr int NKV = 8;
static constexpr int HD  = 64;
static constexpr int Md  = Bd * Td;     // 4096 rows

__device__ inline float bf2f(unsigned short u) {
  union { unsigned int i; float f; } v; v.i = ((unsigned int)u) << 16; return v.f;
}
__device__ inline unsigned short f2bfbits(float f) {
  union { float f; unsigned int u; } v; v.f = f;
  unsigned int r = v.u + 0x7fffu + ((v.u >> 16) & 1u);   // RNE
  return (unsigned short)(r >> 16);
}
__device__ inline unsigned int pkbf(float a, float b) {   // lo=bf16(a), hi=bf16(b)
  unsigned int r;
  asm("v_cvt_pk_bf16_f32 %0, %1, %2" : "=v"(r) : "v"(a), "v"(b));
  return r;
}
// v_permlane32_swap_b32 d, s:  d.hi <-> s.lo.
// After: d = {d.lo, s.lo}, s = {d.hi, s.hi}.
__device__ inline void plswapf(float& a, float& b) {
  asm("v_permlane32_swap_b32 %0, %1" : "+v"(a), "+v"(b));
}
__device__ inline void plswapu(unsigned int& a, unsigned int& b) {
  asm("v_permlane32_swap_b32 %0, %1" : "+v"(a), "+v"(b));
}
__device__ inline float hmax16(const f32x16& v) {
  float a0 = fmaxf(v[0], v[1]),   a1 = fmaxf(v[2], v[3]);
  float a2 = fmaxf(v[4], v[5]),   a3 = fmaxf(v[6], v[7]);
  float a4 = fmaxf(v[8], v[9]),   a5 = fmaxf(v[10], v[11]);
  float a6 = fmaxf(v[12], v[13]), a7 = fmaxf(v[14], v[15]);
  float b0 = fmaxf(a0, a1), b1 = fmaxf(a2, a3);
  float b2 = fmaxf(a4, a5), b3 = fmaxf(a6, a7);
  return fmaxf(fmaxf(b0, b1), fmaxf(b2, b3));
}
__device__ inline float hsum16(const f32x16& v) {
  float a0 = v[0]+v[1],   a1 = v[2]+v[3],   a2 = v[4]+v[5],   a3 = v[6]+v[7];
  float a4 = v[8]+v[9],   a5 = v[10]+v[11], a6 = v[12]+v[13], a7 = v[14]+v[15];
  float b0 = a0+a1, b1 = a2+a3, b2 = a4+a5, b3 = a6+a7;
  return (b0+b1)+(b2+b3);
}

// ---------------- fp32 -> bf16 (vectorized) --------------------------------
__global__ __launch_bounds__(256) void f2b_kernel(const float* __restrict__ in,
                                                  bf16* __restrict__ out, int n4) {
  int i = blockIdx.x * 256 + threadIdx.x;
  if (i >= n4) return;
  float4 v = ((const float4*)in)[i];
  ushort4 o;
  o.x = f2bfbits(v.x); o.y = f2bfbits(v.y); o.z = f2bfbits(v.z); o.w = f2bfbits(v.w);
  ((ushort4*)out)[i] = o;
}

// ---------------- fp32 [R][Cc] -> bf16 transpose [Cc][R] -------------------
__global__ __launch_bounds__(256) void transpose_f2b(const float* __restrict__ in,
                                                     bf16* __restrict__ out,
                                                     int R, int Cc) {
  __shared__ float tile[32][33];
  int tx = threadIdx.x, ty = threadIdx.y;
  int bx = blockIdx.x, by = blockIdx.y;
  int col = bx * 32 + tx;
#pragma unroll
  for (int i = 0; i < 4; ++i) {
    int row = by * 32 + ty + i * 8;
    tile[ty + i * 8][tx] = in[(size_t)row * Cc + col];
  }
  __syncthreads();
#pragma unroll
  for (int i = 0; i < 4; ++i) {
    int orow = bx * 32 + ty + i * 8;   // original col
    int ocol = by * 32 + tx;           // original row
    out[(size_t)orow * R + ocol] = __float2bfloat16(tile[tx][ty + i * 8]);
  }
}

// ---------------- GEMM: C[M][N] = A[M][K] * Bt[N][K]^T ---------------------
// 128x128 tile, BK=32, 4 waves (2x2), 4x4 16x16 frags per wave.
// MODE 2: fp32 row-major [M][N].  MODE 3: fused QKV epilogue.
template <int MODE>
__global__ __launch_bounds__(256) void gemm_bf16(const bf16* __restrict__ A,
                                                 const bf16* __restrict__ Bt,
                                                 void* __restrict__ Cp,
                                                 int M, int N, int K) {
  __shared__ bf16 Al[128 * 32];
  __shared__ bf16 Bl[128 * 32];
  int tid = threadIdx.x;
  int w = tid >> 6, lane = tid & 63;
  int lr = lane & 15, lg = lane >> 4;
  int m0 = blockIdx.x * 128, n0 = blockIdx.y * 128;
  int wr = w >> 1, wc = w & 1;
  f32x4 acc[4][4] = {};

  const bf16* Aw = A + (size_t)m0 * K;
  const bf16* Bw = Bt + (size_t)n0 * K;
  int srow = (lane >> 2);          // 0..15 within segment
  int scol = (lane & 3) * 8;       // 0,8,16,24

  for (int kt = 0; kt < K; kt += 32) {
#pragma unroll
    for (int r = 0; r < 2; ++r) {
      int seg = r * 4 + w;                 // 0..7 -> 16 rows each
      int row = seg * 16 + srow;
      GLOAD_LDS16(Aw + (size_t)row * K + kt + scol, &Al[seg * 512]);
      GLOAD_LDS16(Bw + (size_t)row * K + kt + scol, &Bl[seg * 512]);
    }
    __syncthreads();
    short8 af[4], bfr[4];
#pragma unroll
    for (int f = 0; f < 4; ++f) {
      af[f]  = *(const short8*)&Al[(wr * 64 + f * 16 + lr) * 32 + lg * 8];
      bfr[f] = *(const short8*)&Bl[(wc * 64 + f * 16 + lr) * 32 + lg * 8];
    }
#pragma unroll
    for (int i = 0; i < 4; ++i)
#pragma unroll
      for (int j = 0; j < 4; ++j)
        acc[i][j] = __builtin_amdgcn_mfma_f32_16x16x32_bf16(af[i], bfr[j], acc[i][j], 0, 0, 0);
    __syncthreads();
  }

  bf16* Qb  = (bf16*)Cp;
  bf16* Kb  = Qb + (size_t)Bd * NH * Td * HD;
  bf16* Vtb = Kb + (size_t)Bd * NKV * Td * HD;

#pragma unroll
  for (int i = 0; i < 4; ++i) {
#pragma unroll
    for (int j = 0; j < 4; ++j) {
#pragma unroll
      for (int r = 0; r < 4; ++r) {
        int mrow = m0 + wr * 64 + i * 16 + lg * 4 + r;
        int ncol = n0 + wc * 64 + j * 16 + lr;
        float v = acc[i][j][r];
        if (MODE == 2) {
          ((float*)Cp)[(size_t)mrow * N + ncol] = v;
        } else {
          int b = mrow >> 11, t = mrow & 2047;
          if (n0 < 2048) {             // Q: [B][32][T][64]
            int h = ncol >> 6, d = ncol & 63;
            Qb[(((size_t)b * NH + h) * Td + t) * HD + d] = __float2bfloat16(v);
          } else if (n0 < 2560) {      // K: [B][8][T][64]
            int cc = ncol - 2048;
            int h = cc >> 6, d = cc & 63;
            Kb[(((size_t)b * NKV + h) * Td + t) * HD + d] = __float2bfloat16(v);
          } else {                     // V^T: [B][8][64][T]
            int cc = ncol - 2560;
            int h = cc >> 6, d = cc & 63;
            Vtb[(((size_t)b * NKV + h) * HD + d) * Td + t] = __float2bfloat16(v);
          }
        }
      }
    }
  }
}

// ---------------- RoPE (in-place, native trig; Q pre-scaled) ---------------
__global__ __launch_bounds__(256) void rope_kernel(bf16* __restrict__ Q,
                                                   bf16* __restrict__ K,
                                                   int qpairs, int total) {
  int i = blockIdx.x * 256 + threadIdx.x;
  if (i >= total) return;
  unsigned int* buf; int p; float sc;
  if (i < qpairs) { buf = (unsigned int*)Q; p = i; sc = 0.18033688011112042f; } // 0.125*log2e
  else            { buf = (unsigned int*)K; p = i - qpairs; sc = 1.0f; }
  int d2 = p & 31;             // pair index within head dim (D/2 = 32)
  int t  = (p >> 5) & (Td - 1);
  unsigned int packed = buf[p];
  float xe = bf2f((unsigned short)(packed & 0xffffu));
  float xo = bf2f((unsigned short)(packed >> 16));
  // inv_freq = 10000^(-d2/32) = exp2(-d2 * log2(10000)/32)
  float inv = __builtin_amdgcn_exp2f((float)d2 * (-13.287712379549449f / 32.0f));
  float ang = (float)t * inv;
  float rev = ang * 0.15915494309189535f;     // radians -> revolutions
  rev = rev - floorf(rev);
  float s = __builtin_amdgcn_sinf(rev);
  float c = __builtin_amdgcn_cosf(rev);
  float re = (xe * c - xo * s) * sc;
  float ro = (xo * c + xe * s) * sc;
  buf[p] = (unsigned int)f2bfbits(re) | ((unsigned int)f2bfbits(ro) << 16);
}

// ---------------- Flash attention (causal, GQA), swapped-QK 32x32 ----------
// grid (B*NH=64, T/64=32), 256 thr = 4 waves = 2 q-tiles x 2 kv-splits.
// Wave (a,s): q-tile a (rows q0=qt*64+a*32), kv tiles jt = s, s+2, ...
// Online-softmax partials merged through LDS at the end (split-KV merge).
// LPT: qt = 31 - blockIdx.y (heavy blocks first).
// S^T = mfma(K, Q): row=kv=(rr&3)+8*(rr>>2)+4*(lane>>5), col=q=lane&31.
// O^T = mfma(V^T, P): row=d (same formula), col=q.
// Q is pre-scaled by 0.125*log2(e) (rope_kernel); softmax in exp2 domain.
__global__ __launch_bounds__(256) void attn_kernel(const bf16* __restrict__ Q,
                                                   const bf16* __restrict__ K,
                                                   const bf16* __restrict__ Vt,
                                                   bf16* __restrict__ Y) {
  __shared__ __align__(16) float Osh[2][64 * 36];   // [tile][lane*36 + 0..31]
  __shared__ float MLsh[2][2][64];                  // [tile][m/l][lane]
  int tid = threadIdx.x, w = tid >> 6, lane = tid & 63;
  int lq = lane & 31;          // q column
  int H  = lane >> 5;          // lane half
  int a  = w >> 1, s = w & 1;  // q-tile, kv-split
  int qt = 31 - (int)blockIdx.y;
  int bh = blockIdx.x;
  int b = bh >> 5, h = bh & 31, kvh = h >> 2;
  int q0 = qt * 64 + a * 32;
  int qg = q0 + lq;

  const bf16* Qp = Q + (((size_t)b * NH + h) * Td) * HD;
  const bf16* Kp = K + (((size_t)b * NKV + kvh) * Td) * HD;
  const bf16* Vp = Vt + (((size_t)b * NKV + kvh) * HD) * Td;

  // Q B-fragments (already scaled): qf[ck][j] = Q[qg][ck*16+H*8+j]
  short8 qf[4];
#pragma unroll
  for (int ck = 0; ck < 4; ++ck)
    qf[ck] = *(const short8*)(Qp + (size_t)qg * HD + ck * 16 + H * 8);

  f32x16 acc0 = {}, acc1 = {};     // O^T[d][q], d-tiles 0..31 / 32..63
  float m = -3e38f, l = 0.0f;
  int nkv = qt + 1;

  for (int jt = s; jt < nkv; jt += 2) {
    int kvb = jt * 64;
    // ---- S^T = K . Q^T  (2 kv-subtiles x 4 k-chunks) ----
    f32x16 s0 = {}, s1 = {};
    const bf16* K0 = Kp + (size_t)(kvb + lq) * HD + H * 8;
    __builtin_amdgcn_s_setprio(1);
#pragma unroll
    for (int ck = 0; ck < 4; ++ck) {
      short8 kf0 = *(const short8*)(K0 + ck * 16);
      short8 kf1 = *(const short8*)(K0 + (size_t)32 * HD + ck * 16);
      s0 = MFMA32(kf0, qf[ck], s0);
      s1 = MFMA32(kf1, qf[ck], s1);
    }
    __builtin_amdgcn_s_setprio(0);
    // ---- causal mask (diagonal tile only) ----
    if (jt == nkv - 1) {
#pragma unroll
      for (int rr = 0; rr < 16; ++rr) {
        int krel = (rr & 3) + 8 * (rr >> 2) + 4 * H;
        if (kvb + krel > qg)      s0[rr] = -3e38f;
        if (kvb + 32 + krel > qg) s1[rr] = -3e38f;
      }
    }
    // ---- row max: register tree + cross-half permlane swap ----
    float mx = fmaxf(hmax16(s0), hmax16(s1));
    {
      float mb = mx;
      asm("" : "+v"(mb));          // force distinct reg for the copy
      plswapf(mx, mb);             // mx={lo,lo}, mb={hi,hi}
      mx = fmaxf(mx, mb);
    }
    // ---- defer-rescale (T13, THR=8 in log2 domain) ----
    if (__any(mx > m + 8.0f)) {
      float mn = fmaxf(m, mx);
      float al = __builtin_amdgcn_exp2f(m - mn);
      m = mn;
      l *= al;
#pragma unroll
      for (int rr = 0; rr < 16; ++rr) { acc0[rr] *= al; acc1[rr] *= al; }
    }
    // ---- p = exp2(s - m) (masked -> 0 via underflow) ----
#pragma unroll
    for (int rr = 0; rr < 16; ++rr) {
      s0[rr] = __builtin_amdgcn_exp2f(s0[rr] - m);
      s1[rr] = __builtin_amdgcn_exp2f(s1[rr] - m);
    }
    float ps = hsum16(s0) + hsum16(s1);
    {
      float pb = ps;
      asm("" : "+v"(pb));
      plswapf(ps, pb);
      ps += pb;
    }
    l += ps;
    // ---- pack P to bf16 B-fragments: cvt_pk + permlane32_swap (T12) ----
    // swap(A0,B0): A0 -> word0 = {A0.lo,B0.lo}, B0 -> word2 = {A0.hi,B0.hi}.
    short8 pf[4];
#pragma unroll
    for (int t = 0; t < 2; ++t) {
      const f32x16& sv = t ? s1 : s0;
#pragma unroll
      for (int a2 = 0; a2 < 2; ++a2) {
        unsigned int A0 = pkbf(sv[8*a2 + 0], sv[8*a2 + 1]);
        unsigned int A1 = pkbf(sv[8*a2 + 2], sv[8*a2 + 3]);
        unsigned int B0 = pkbf(sv[8*a2 + 4], sv[8*a2 + 5]);
        unsigned int B1 = pkbf(sv[8*a2 + 6], sv[8*a2 + 7]);
        plswapu(A0, B0);
        plswapu(A1, B1);
        u32x4 t4;
        t4[0] = A0; t4[1] = A1; t4[2] = B0; t4[3] = B1;
        pf[2*t + a2] = __builtin_bit_cast(short8, t4);
      }
    }
    // ---- O^T += V^T . P  (2 d-subtiles x 4 kv-chunks) ----
    const bf16* V0 = Vp + (size_t)lq * Td + kvb + H * 8;
    __builtin_amdgcn_s_setprio(1);
#pragma unroll
    for (int ks = 0; ks < 4; ++ks) {
      short8 vf0 = *(const short8*)(V0 + ks * 16);
      short8 vf1 = *(const short8*)(V0 + (size_t)32 * Td + ks * 16);
      acc0 = MFMA32(vf0, pf[ks], acc0);
      acc1 = MFMA32(vf1, pf[ks], acc1);
    }
    __builtin_amdgcn_s_setprio(0);
  }

  // ---- split-KV merge: wave s=1 publishes partials; s=0 merges + writes ----
  if (s == 1) {
    MLsh[a][0][lane] = m;
    MLsh[a][1][lane] = l;
    float* ob = &Osh[a][lane * 36];
#pragma unroll
    for (int c = 0; c < 4; ++c) {
      float4 t0; t0.x = acc0[4*c]; t0.y = acc0[4*c+1]; t0.z = acc0[4*c+2]; t0.w = acc0[4*c+3];
      ((float4*)ob)[c] = t0;
      float4 t1; t1.x = acc1[4*c]; t1.y = acc1[4*c+1]; t1.z = acc1[4*c+2]; t1.w = acc1[4*c+3];
      ((float4*)ob)[4 + c] = t1;
    }
  }
  __syncthreads();
  if (s == 0) {
    float m1 = MLsh[a][0][lane], l1 = MLsh[a][1][lane];
    float M  = fmaxf(m, m1);
    float e0 = __builtin_amdgcn_exp2f(m - M);
    float e1 = __builtin_amdgcn_exp2f(m1 - M);
    float L  = l * e0 + l1 * e1;
    float rn = 1.0f / L;
    const float* ob = &Osh[a][lane * 36];
    float pa[32];
#pragma unroll
    for (int c = 0; c < 8; ++c)
      *(float4*)&pa[4*c] = ((const float4*)ob)[c];
    bf16* Yp = Y + ((size_t)b * Td + qg) * Cd + h * HD;
#pragma unroll
    for (int rr = 0; rr < 16; rr += 2) {
      int d = (rr & 3) + 8 * (rr >> 2) + 4 * H;   // d, d+1 for rr, rr+1
      float o0 = (acc0[rr]     * e0 + pa[rr]      * e1) * rn;
      float o1 = (acc0[rr + 1] * e0 + pa[rr + 1]  * e1) * rn;
      float u0 = (acc1[rr]     * e0 + pa[16 + rr]     * e1) * rn;
      float u1 = (acc1[rr + 1] * e0 + pa[16 + rr + 1] * e1) * rn;
      *(unsigned int*)(Yp + d)      = pkbf(o0, o1);
      *(unsigned int*)(Yp + 32 + d) = pkbf(u0, u1);
    }
  }
}

// ---------------------------------------------------------------------------
extern "C" void kernel_launch(void* const* d_in, const int* in_sizes, int n_in,
                              void* d_out, int out_size, void* d_ws, size_t ws_size,
                              hipStream_t stream) {
  const float* x  = (const float*)d_in[0];
  const float* wq = (const float*)d_in[1];
  const float* wk = (const float*)d_in[2];
  const float* wv = (const float*)d_in[3];
  const float* wo = (const float*)d_in[4];

  char* ws = (char*)d_ws;
  const size_t o_xb = 0;                                   // 16.78 MB (reused as yb)
  const size_t o_w1 = o_xb + (size_t)Md * Cd * 2;          // 12.58 MB (wqkvT / later woT)
  const size_t o_Q  = o_w1 + (size_t)3072 * Cd * 2;        // 16.78 MB
  const size_t o_K  = o_Q + (size_t)Bd * NH * Td * HD * 2; // 4.19 MB
  const size_t o_V  = o_K + (size_t)Bd * NKV * Td * HD * 2;// 4.19 MB

  bf16* xb  = (bf16*)(ws + o_xb);
  bf16* w1  = (bf16*)(ws + o_w1);
  bf16* Qb  = (bf16*)(ws + o_Q);
  bf16* Kb  = (bf16*)(ws + o_K);
  bf16* Vtb = (bf16*)(ws + o_V);
  bf16* yb  = xb;   // alias: x_bf16 dead after QKV GEMM

  // 1. x -> bf16
  {
    int n4 = (Md * Cd) / 4;
    f2b_kernel<<<dim3((n4 + 255) / 256), dim3(256), 0, stream>>>(x, xb, n4);
  }
  // 2. weight transposes (fp32 -> bf16^T) into one [3072][2048] buffer
  transpose_f2b<<<dim3(Cd / 32, Cd / 32), dim3(32, 8), 0, stream>>>(wq, w1, Cd, Cd);
  transpose_f2b<<<dim3(512 / 32, Cd / 32), dim3(32, 8), 0, stream>>>(wk, w1 + (size_t)2048 * Cd, Cd, 512);
  transpose_f2b<<<dim3(512 / 32, Cd / 32), dim3(32, 8), 0, stream>>>(wv, w1 + (size_t)2560 * Cd, Cd, 512);
  // 3. fused QKV projection (N = 3072)
  gemm_bf16<3><<<dim3(Md / 128, 3072 / 128), dim3(256), 0, stream>>>(xb, w1, Qb, Md, 3072, Cd);
  // 4. wo transpose into w1 (wqkvT dead after GEMM)
  transpose_f2b<<<dim3(Cd / 32, Cd / 32), dim3(32, 8), 0, stream>>>(wo, w1, Cd, Cd);
  // 5. RoPE on Q and K (in place; Q pre-scaled by 0.125*log2e)
  {
    int qpairs = Bd * NH * Td * HD / 2;
    int kpairs = Bd * NKV * Td * HD / 2;
    int total = qpairs + kpairs;
    rope_kernel<<<dim3((total + 255) / 256), dim3(256), 0, stream>>>(Qb, Kb, qpairs, total);
  }
  // 6. attention -> yb (bf16 [M][C]); 4-wave blocks (2 q-tiles x 2 kv-splits)
  attn_kernel<<<dim3(Bd * NH, Td / 64), dim3(256), 0, stream>>>(Qb, Kb, Vtb, yb);
  // 7. output projection -> d_out (fp32)
  gemm_bf16<2><<<dim3(Md / 128, Cd / 128), dim3(256), 0, stream>>>(yb, w1, d_out, Md, Cd, Cd);
}

// Round 5
// 234.599 us; speedup vs baseline: 1.2951x; 1.2951x over previous
//
#include <hip/hip_runtime.h>
#include <hip/hip_bf16.h>
#include <cstdint>
#include <cstddef>

// ---------------------------------------------------------------------------
// LlamaAttention forward: out = Attn(RoPE(x@wq), RoPE(x@wk), x@wv) @ wo
// B=2 T=2048 C=2048 NH=32 NKV=8 D=64, causal, GQA rep=4, scale=1/8.
// R5: attn -> 8-wave blocks (256 q-rows), K/V staged in LDS once per block
// via coalesced global_load_lds (inverse-swizzled source, XOR-swizzled
// ds_read), 2-phase double buffer. Fixes the uncoalesced-global-read
// TA-pipe saturation seen in R3/R4 (strided 16B/lane reads).
// ---------------------------------------------------------------------------

using bf16 = __hip_bfloat16;
using f32x4  = __attribute__((ext_vector_type(4))) float;
using f32x16 = __attribute__((ext_vector_type(16))) float;
using short8 = __attribute__((ext_vector_type(8))) short;
using u32x4  = __attribute__((ext_vector_type(4))) unsigned int;

typedef __attribute__((address_space(1))) const void* gp1_t;
typedef __attribute__((address_space(3))) void*       lp3_t;

#define GLOAD_LDS16(g, l)                                                     \
  __builtin_amdgcn_global_load_lds((gp1_t)(const void*)(g), (lp3_t)(void*)(l), 16, 0, 0)

#define MFMA32(a, b, c) __builtin_amdgcn_mfma_f32_32x32x16_bf16(a, b, c, 0, 0, 0)

static constexpr int Bd  = 2;
static constexpr int Td  = 2048;
static constexpr int Cd  = 2048;
static constexpr int NH  = 32;
static constexpr int NKV = 8;
static constexpr int HD  = 64;
static constexpr int Md  = Bd * Td;     // 4096 rows

__device__ inline float bf2f(unsigned short u) {
  union { unsigned int i; float f; } v; v.i = ((unsigned int)u) << 16; return v.f;
}
__device__ inline unsigned short f2bfbits(float f) {
  union { float f; unsigned int u; } v; v.f = f;
  unsigned int r = v.u + 0x7fffu + ((v.u >> 16) & 1u);   // RNE
  return (unsigned short)(r >> 16);
}
__device__ inline unsigned int pkbf(float a, float b) {   // lo=bf16(a), hi=bf16(b)
  unsigned int r;
  asm("v_cvt_pk_bf16_f32 %0, %1, %2" : "=v"(r) : "v"(a), "v"(b));
  return r;
}
// v_permlane32_swap_b32 d, s:  after: d = {d.lo, s.lo}, s = {d.hi, s.hi}.
__device__ inline void plswapf(float& a, float& b) {
  asm("v_permlane32_swap_b32 %0, %1" : "+v"(a), "+v"(b));
}
__device__ inline void plswapu(unsigned int& a, unsigned int& b) {
  asm("v_permlane32_swap_b32 %0, %1" : "+v"(a), "+v"(b));
}
__device__ inline float hmax16(const f32x16& v) {
  float a0 = fmaxf(v[0], v[1]),   a1 = fmaxf(v[2], v[3]);
  float a2 = fmaxf(v[4], v[5]),   a3 = fmaxf(v[6], v[7]);
  float a4 = fmaxf(v[8], v[9]),   a5 = fmaxf(v[10], v[11]);
  float a6 = fmaxf(v[12], v[13]), a7 = fmaxf(v[14], v[15]);
  float b0 = fmaxf(a0, a1), b1 = fmaxf(a2, a3);
  float b2 = fmaxf(a4, a5), b3 = fmaxf(a6, a7);
  return fmaxf(fmaxf(b0, b1), fmaxf(b2, b3));
}
__device__ inline float hsum16(const f32x16& v) {
  float a0 = v[0]+v[1],   a1 = v[2]+v[3],   a2 = v[4]+v[5],   a3 = v[6]+v[7];
  float a4 = v[8]+v[9],   a5 = v[10]+v[11], a6 = v[12]+v[13], a7 = v[14]+v[15];
  float b0 = a0+a1, b1 = a2+a3, b2 = a4+a5, b3 = a6+a7;
  return (b0+b1)+(b2+b3);
}

// ---------------- fp32 -> bf16 (vectorized) --------------------------------
__global__ __launch_bounds__(256) void f2b_kernel(const float* __restrict__ in,
                                                  bf16* __restrict__ out, int n4) {
  int i = blockIdx.x * 256 + threadIdx.x;
  if (i >= n4) return;
  float4 v = ((const float4*)in)[i];
  ushort4 o;
  o.x = f2bfbits(v.x); o.y = f2bfbits(v.y); o.z = f2bfbits(v.z); o.w = f2bfbits(v.w);
  ((ushort4*)out)[i] = o;
}

// ---------------- fp32 [R][Cc] -> bf16 transpose [Cc][R] -------------------
__global__ __launch_bounds__(256) void transpose_f2b(const float* __restrict__ in,
                                                     bf16* __restrict__ out,
                                                     int R, int Cc) {
  __shared__ float tile[32][33];
  int tx = threadIdx.x, ty = threadIdx.y;
  int bx = blockIdx.x, by = blockIdx.y;
  int col = bx * 32 + tx;
#pragma unroll
  for (int i = 0; i < 4; ++i) {
    int row = by * 32 + ty + i * 8;
    tile[ty + i * 8][tx] = in[(size_t)row * Cc + col];
  }
  __syncthreads();
#pragma unroll
  for (int i = 0; i < 4; ++i) {
    int orow = bx * 32 + ty + i * 8;   // original col
    int ocol = by * 32 + tx;           // original row
    out[(size_t)orow * R + ocol] = __float2bfloat16(tile[tx][ty + i * 8]);
  }
}

// ---------------- GEMM: C[M][N] = A[M][K] * Bt[N][K]^T ---------------------
// 128x128 tile, BK=32, 4 waves (2x2), 4x4 16x16 frags per wave.
// MODE 2: fp32 row-major [M][N].  MODE 3: fused QKV epilogue.
template <int MODE>
__global__ __launch_bounds__(256) void gemm_bf16(const bf16* __restrict__ A,
                                                 const bf16* __restrict__ Bt,
                                                 void* __restrict__ Cp,
                                                 int M, int N, int K) {
  __shared__ bf16 Al[128 * 32];
  __shared__ bf16 Bl[128 * 32];
  int tid = threadIdx.x;
  int w = tid >> 6, lane = tid & 63;
  int lr = lane & 15, lg = lane >> 4;
  int m0 = blockIdx.x * 128, n0 = blockIdx.y * 128;
  int wr = w >> 1, wc = w & 1;
  f32x4 acc[4][4] = {};

  const bf16* Aw = A + (size_t)m0 * K;
  const bf16* Bw = Bt + (size_t)n0 * K;
  int srow = (lane >> 2);          // 0..15 within segment
  int scol = (lane & 3) * 8;       // 0,8,16,24

  for (int kt = 0; kt < K; kt += 32) {
#pragma unroll
    for (int r = 0; r < 2; ++r) {
      int seg = r * 4 + w;                 // 0..7 -> 16 rows each
      int row = seg * 16 + srow;
      GLOAD_LDS16(Aw + (size_t)row * K + kt + scol, &Al[seg * 512]);
      GLOAD_LDS16(Bw + (size_t)row * K + kt + scol, &Bl[seg * 512]);
    }
    __syncthreads();
    short8 af[4], bfr[4];
#pragma unroll
    for (int f = 0; f < 4; ++f) {
      af[f]  = *(const short8*)&Al[(wr * 64 + f * 16 + lr) * 32 + lg * 8];
      bfr[f] = *(const short8*)&Bl[(wc * 64 + f * 16 + lr) * 32 + lg * 8];
    }
#pragma unroll
    for (int i = 0; i < 4; ++i)
#pragma unroll
      for (int j = 0; j < 4; ++j)
        acc[i][j] = __builtin_amdgcn_mfma_f32_16x16x32_bf16(af[i], bfr[j], acc[i][j], 0, 0, 0);
    __syncthreads();
  }

  bf16* Qb  = (bf16*)Cp;
  bf16* Kb  = Qb + (size_t)Bd * NH * Td * HD;
  bf16* Vtb = Kb + (size_t)Bd * NKV * Td * HD;

#pragma unroll
  for (int i = 0; i < 4; ++i) {
#pragma unroll
    for (int j = 0; j < 4; ++j) {
#pragma unroll
      for (int r = 0; r < 4; ++r) {
        int mrow = m0 + wr * 64 + i * 16 + lg * 4 + r;
        int ncol = n0 + wc * 64 + j * 16 + lr;
        float v = acc[i][j][r];
        if (MODE == 2) {
          ((float*)Cp)[(size_t)mrow * N + ncol] = v;
        } else {
          int b = mrow >> 11, t = mrow & 2047;
          if (n0 < 2048) {             // Q: [B][32][T][64]
            int h = ncol >> 6, d = ncol & 63;
            Qb[(((size_t)b * NH + h) * Td + t) * HD + d] = __float2bfloat16(v);
          } else if (n0 < 2560) {      // K: [B][8][T][64]
            int cc = ncol - 2048;
            int h = cc >> 6, d = cc & 63;
            Kb[(((size_t)b * NKV + h) * Td + t) * HD + d] = __float2bfloat16(v);
          } else {                     // V^T: [B][8][64][T]
            int cc = ncol - 2560;
            int h = cc >> 6, d = cc & 63;
            Vtb[(((size_t)b * NKV + h) * HD + d) * Td + t] = __float2bfloat16(v);
          }
        }
      }
    }
  }
}

// ---------------- RoPE (in-place, native trig; Q pre-scaled) ---------------
__global__ __launch_bounds__(256) void rope_kernel(bf16* __restrict__ Q,
                                                   bf16* __restrict__ K,
                                                   int qpairs, int total) {
  int i = blockIdx.x * 256 + threadIdx.x;
  if (i >= total) return;
  unsigned int* buf; int p; float sc;
  if (i < qpairs) { buf = (unsigned int*)Q; p = i; sc = 0.18033688011112042f; } // 0.125*log2e
  else            { buf = (unsigned int*)K; p = i - qpairs; sc = 1.0f; }
  int d2 = p & 31;             // pair index within head dim (D/2 = 32)
  int t  = (p >> 5) & (Td - 1);
  unsigned int packed = buf[p];
  float xe = bf2f((unsigned short)(packed & 0xffffu));
  float xo = bf2f((unsigned short)(packed >> 16));
  // inv_freq = 10000^(-d2/32) = exp2(-d2 * log2(10000)/32)
  float inv = __builtin_amdgcn_exp2f((float)d2 * (-13.287712379549449f / 32.0f));
  float ang = (float)t * inv;
  float rev = ang * 0.15915494309189535f;     // radians -> revolutions
  rev = rev - floorf(rev);
  float s = __builtin_amdgcn_sinf(rev);
  float c = __builtin_amdgcn_cosf(rev);
  float re = (xe * c - xo * s) * sc;
  float ro = (xo * c + xe * s) * sc;
  buf[p] = (unsigned int)f2bfbits(re) | ((unsigned int)f2bfbits(ro) << 16);
}

// ---------------- Flash attention (causal, GQA), LDS-staged KV -------------
// grid (B*NH=64, 8 qb), 512 thr = 8 waves; wave w owns q rows qb*256+w*32..+31.
// LPT: qb = 7 - blockIdx.y (heavy blocks first).
// Per kv tile (64x64): wave w stages K rows [w*8,w*8+8) and Vt rows [w*8,+8)
// via ONE global_load_lds dwordx4 each (coalesced), with inverse-XOR-swizzled
// global source so XOR-swizzled ds_reads (byte ^= (row&7)<<4) are linear.
// 2-phase double buffer: STAGE(next) -> compute(cur) -> vmcnt(0)+barrier.
// Softmax: swapped QK^T (S^T col=q=lane&31), in-register, T12 pack, T13 defer.
__global__ __launch_bounds__(512, 4) void attn_kernel(const bf16* __restrict__ Q,
                                                      const bf16* __restrict__ K,
                                                      const bf16* __restrict__ Vt,
                                                      bf16* __restrict__ Y) {
  __shared__ __align__(16) char lds[2 * 16384];   // [buf][K 8KB | V 8KB]
  int tid = threadIdx.x, w = tid >> 6, lane = tid & 63;
  int lq = lane & 31;          // q column (and kv/d row within subtile)
  int H  = lane >> 5;          // lane half
  int qb = 7 - (int)blockIdx.y;
  int bh = blockIdx.x;
  int b = bh >> 5, h = bh & 31, kvh = h >> 2;
  int q0w = qb * 256 + w * 32;
  int qg  = q0w + lq;
  int tmax = qb * 4 + (w >> 1);    // this wave's last compute tile
  int Nt   = qb * 4 + 4;           // tiles staged by the block

  const bf16* Qp = Q + (((size_t)b * NH + h) * Td) * HD;
  const char* Kg = (const char*)(K + (((size_t)b * NKV + kvh) * Td) * HD);   // rows 128B
  const char* Vg = (const char*)(Vt + (((size_t)b * NKV + kvh) * HD) * Td);  // rows 4096B

  // Q B-fragments (pre-scaled in rope): qf[ck][j] = Q[qg][ck*16+H*8+j]
  short8 qf[4];
#pragma unroll
  for (int ck = 0; ck < 4; ++ck)
    qf[ck] = *(const short8*)(Qp + (size_t)qg * HD + ck * 16 + H * 8);

  // staging geometry: wave w stages tile rows [w*8, w*8+8), 16B per lane
  int srow   = lane >> 3;                       // 0..7 within the 8-row slab
  int scol16 = ((lane & 7) ^ srow) << 4;        // inverse-swizzled byte col
  const char* Ksrc0 = Kg + (size_t)(w * 8 + srow) * 128 + scol16;
  const char* Vsrc0 = Vg + (size_t)(w * 8 + srow) * 4096 + scol16;
  char* KldsW[2] = { lds + w * 1024,          lds + 16384 + w * 1024 };
  char* VldsW[2] = { lds + 8192 + w * 1024,   lds + 24576 + w * 1024 };

#define STAGE_KV(tt, bb) do {                                                 \
    GLOAD_LDS16(Ksrc0 + (size_t)(tt) * 64 * 128, KldsW[bb]);                  \
    GLOAD_LDS16(Vsrc0 + (size_t)(tt) * 128,      VldsW[bb]);                  \
  } while (0)

  f32x16 acc0 = {}, acc1 = {};     // O^T[d][q], d 0..31 / 32..63
  float m = -3e38f, l = 0.0f;
  int swz = (lq & 7) << 4;
  int rb0 = lq * 128, rb1 = (32 + lq) * 128;

  STAGE_KV(0, 0);
  asm volatile("s_waitcnt vmcnt(0)" ::: "memory");
  __syncthreads();

  for (int t = 0; t < Nt; ++t) {
    int cur = t & 1;
    if (t + 1 < Nt) STAGE_KV(t + 1, cur ^ 1);
    if (t <= tmax) {
      const char* Kl = lds + cur * 16384;
      const char* Vl = Kl + 8192;
      // ---- S^T = K . Q^T ----
      f32x16 s0 = {}, s1 = {};
      __builtin_amdgcn_s_setprio(1);
#pragma unroll
      for (int ck = 0; ck < 4; ++ck) {
        int c = (H * 16 + ck * 32) ^ swz;
        short8 kf0 = *(const short8*)(Kl + rb0 + c);
        short8 kf1 = *(const short8*)(Kl + rb1 + c);
        s0 = MFMA32(kf0, qf[ck], s0);
        s1 = MFMA32(kf1, qf[ck], s1);
      }
      __builtin_amdgcn_s_setprio(0);
      // ---- causal mask (diagonal tile only) ----
      if (t == tmax) {
        int kvb = t * 64;
#pragma unroll
        for (int rr = 0; rr < 16; ++rr) {
          int krel = (rr & 3) + 8 * (rr >> 2) + 4 * H;
          if (kvb + krel > qg)      s0[rr] = -3e38f;
          if (kvb + 32 + krel > qg) s1[rr] = -3e38f;
        }
      }
      // ---- row max (register tree + cross-half permlane swap) ----
      float mx = fmaxf(hmax16(s0), hmax16(s1));
      {
        float mb = mx;
        asm("" : "+v"(mb));
        plswapf(mx, mb);
        mx = fmaxf(mx, mb);
      }
      // ---- defer-rescale (T13, THR=8 in log2 domain) ----
      if (__any(mx > m + 8.0f)) {
        float mn = fmaxf(m, mx);
        float al = __builtin_amdgcn_exp2f(m - mn);
        m = mn;
        l *= al;
#pragma unroll
        for (int rr = 0; rr < 16; ++rr) { acc0[rr] *= al; acc1[rr] *= al; }
      }
      // ---- p = exp2(s - m) ----
#pragma unroll
      for (int rr = 0; rr < 16; ++rr) {
        s0[rr] = __builtin_amdgcn_exp2f(s0[rr] - m);
        s1[rr] = __builtin_amdgcn_exp2f(s1[rr] - m);
      }
      float ps = hsum16(s0) + hsum16(s1);
      {
        float pb = ps;
        asm("" : "+v"(pb));
        plswapf(ps, pb);
        ps += pb;
      }
      l += ps;
      // ---- pack P -> bf16 B-fragments (T12: cvt_pk + permlane32_swap) ----
      short8 pf[4];
#pragma unroll
      for (int tt = 0; tt < 2; ++tt) {
        const f32x16& sv = tt ? s1 : s0;
#pragma unroll
        for (int a2 = 0; a2 < 2; ++a2) {
          unsigned int A0 = pkbf(sv[8*a2 + 0], sv[8*a2 + 1]);
          unsigned int A1 = pkbf(sv[8*a2 + 2], sv[8*a2 + 3]);
          unsigned int B0 = pkbf(sv[8*a2 + 4], sv[8*a2 + 5]);
          unsigned int B1 = pkbf(sv[8*a2 + 6], sv[8*a2 + 7]);
          plswapu(A0, B0);
          plswapu(A1, B1);
          u32x4 t4;
          t4[0] = A0; t4[1] = A1; t4[2] = B0; t4[3] = B1;
          pf[2*tt + a2] = __builtin_bit_cast(short8, t4);
        }
      }
      // ---- O^T += V^T . P ----
      __builtin_amdgcn_s_setprio(1);
#pragma unroll
      for (int ks = 0; ks < 4; ++ks) {
        int c = (H * 16 + ks * 32) ^ swz;
        short8 vf0 = *(const short8*)(Vl + rb0 + c);
        short8 vf1 = *(const short8*)(Vl + rb1 + c);
        acc0 = MFMA32(vf0, pf[ks], acc0);
        acc1 = MFMA32(vf1, pf[ks], acc1);
      }
      __builtin_amdgcn_s_setprio(0);
    }
    asm volatile("s_waitcnt vmcnt(0)" ::: "memory");
    __syncthreads();
  }
#undef STAGE_KV

  // ---- epilogue: normalize, write Y[M][C] ----
  float rn = 1.0f / l;
  bf16* Yp = Y + ((size_t)b * Td + qg) * Cd + h * HD;
#pragma unroll
  for (int rr = 0; rr < 16; rr += 2) {
    int d = (rr & 3) + 8 * (rr >> 2) + 4 * H;   // d, d+1 for rr, rr+1
    unsigned int w0 = pkbf(acc0[rr] * rn, acc0[rr + 1] * rn);
    unsigned int w1 = pkbf(acc1[rr] * rn, acc1[rr + 1] * rn);
    *(unsigned int*)(Yp + d)      = w0;
    *(unsigned int*)(Yp + 32 + d) = w1;
  }
}

// ---------------------------------------------------------------------------
extern "C" void kernel_launch(void* const* d_in, const int* in_sizes, int n_in,
                              void* d_out, int out_size, void* d_ws, size_t ws_size,
                              hipStream_t stream) {
  const float* x  = (const float*)d_in[0];
  const float* wq = (const float*)d_in[1];
  const float* wk = (const float*)d_in[2];
  const float* wv = (const float*)d_in[3];
  const float* wo = (const float*)d_in[4];

  char* ws = (char*)d_ws;
  const size_t o_xb = 0;                                   // 16.78 MB (reused as yb)
  const size_t o_w1 = o_xb + (size_t)Md * Cd * 2;          // 12.58 MB (wqkvT / later woT)
  const size_t o_Q  = o_w1 + (size_t)3072 * Cd * 2;        // 16.78 MB
  const size_t o_K  = o_Q + (size_t)Bd * NH * Td * HD * 2; // 4.19 MB
  const size_t o_V  = o_K + (size_t)Bd * NKV * Td * HD * 2;// 4.19 MB

  bf16* xb  = (bf16*)(ws + o_xb);
  bf16* w1  = (bf16*)(ws + o_w1);
  bf16* Qb  = (bf16*)(ws + o_Q);
  bf16* Kb  = (bf16*)(ws + o_K);
  bf16* Vtb = (bf16*)(ws + o_V);
  bf16* yb  = xb;   // alias: x_bf16 dead after QKV GEMM

  // 1. x -> bf16
  {
    int n4 = (Md * Cd) / 4;
    f2b_kernel<<<dim3((n4 + 255) / 256), dim3(256), 0, stream>>>(x, xb, n4);
  }
  // 2. weight transposes (fp32 -> bf16^T) into one [3072][2048] buffer
  transpose_f2b<<<dim3(Cd / 32, Cd / 32), dim3(32, 8), 0, stream>>>(wq, w1, Cd, Cd);
  transpose_f2b<<<dim3(512 / 32, Cd / 32), dim3(32, 8), 0, stream>>>(wk, w1 + (size_t)2048 * Cd, Cd, 512);
  transpose_f2b<<<dim3(512 / 32, Cd / 32), dim3(32, 8), 0, stream>>>(wv, w1 + (size_t)2560 * Cd, Cd, 512);
  // 3. fused QKV projection (N = 3072)
  gemm_bf16<3><<<dim3(Md / 128, 3072 / 128), dim3(256), 0, stream>>>(xb, w1, Qb, Md, 3072, Cd);
  // 4. wo transpose into w1 (wqkvT dead after GEMM)
  transpose_f2b<<<dim3(Cd / 32, Cd / 32), dim3(32, 8), 0, stream>>>(wo, w1, Cd, Cd);
  // 5. RoPE on Q and K (in place; Q pre-scaled by 0.125*log2e)
  {
    int qpairs = Bd * NH * Td * HD / 2;
    int kpairs = Bd * NKV * Td * HD / 2;
    int total = qpairs + kpairs;
    rope_kernel<<<dim3((total + 255) / 256), dim3(256), 0, stream>>>(Qb, Kb, qpairs, total);
  }
  // 6. attention -> yb (bf16 [M][C]); 8-wave LDS-staged blocks, LPT order
  attn_kernel<<<dim3(Bd * NH, 8), dim3(512), 0, stream>>>(Qb, Kb, Vtb, yb);
  // 7. output projection -> d_out (fp32)
  gemm_bf16<2><<<dim3(Md / 128, Cd / 128), dim3(256), 0, stream>>>(yb, w1, d_out, Md, Cd, Cd);
}

// Round 6
// 228.953 us; speedup vs baseline: 1.3270x; 1.0247x over previous
//
#include <hip/hip_runtime.h>
#include <hip/hip_bf16.h>
#include <cstdint>
#include <cstddef>

// ---------------------------------------------------------------------------
// LlamaAttention forward: out = Attn(RoPE(x@wq), RoPE(x@wk), x@wv) @ wo
// B=2 T=2048 C=2048 NH=32 NKV=8 D=64, causal, GQA rep=4, scale=1/8.
// R6: GEMM upgrade — BK=64 with both-sides XOR swizzle (conflict-free
// ds_read_b128, rule #21), T1 XCD-aware block swizzle, V^T epilogue via
// wave-private LDS transpose (coalesced dwordx4 stores instead of 4KB-stride
// scalar stores). attn/rope/f2b/transpose unchanged from R5.
// ---------------------------------------------------------------------------

using bf16 = __hip_bfloat16;
using f32x4  = __attribute__((ext_vector_type(4))) float;
using f32x16 = __attribute__((ext_vector_type(16))) float;
using short8 = __attribute__((ext_vector_type(8))) short;
using u32x4  = __attribute__((ext_vector_type(4))) unsigned int;

typedef __attribute__((address_space(1))) const void* gp1_t;
typedef __attribute__((address_space(3))) void*       lp3_t;

#define GLOAD_LDS16(g, l)                                                     \
  __builtin_amdgcn_global_load_lds((gp1_t)(const void*)(g), (lp3_t)(void*)(l), 16, 0, 0)

#define MFMA32(a, b, c) __builtin_amdgcn_mfma_f32_32x32x16_bf16(a, b, c, 0, 0, 0)

static constexpr int Bd  = 2;
static constexpr int Td  = 2048;
static constexpr int Cd  = 2048;
static constexpr int NH  = 32;
static constexpr int NKV = 8;
static constexpr int HD  = 64;
static constexpr int Md  = Bd * Td;     // 4096 rows

__device__ inline float bf2f(unsigned short u) {
  union { unsigned int i; float f; } v; v.i = ((unsigned int)u) << 16; return v.f;
}
__device__ inline unsigned short f2bfbits(float f) {
  union { float f; unsigned int u; } v; v.f = f;
  unsigned int r = v.u + 0x7fffu + ((v.u >> 16) & 1u);   // RNE
  return (unsigned short)(r >> 16);
}
__device__ inline unsigned int pkbf(float a, float b) {   // lo=bf16(a), hi=bf16(b)
  unsigned int r;
  asm("v_cvt_pk_bf16_f32 %0, %1, %2" : "=v"(r) : "v"(a), "v"(b));
  return r;
}
// v_permlane32_swap_b32 d, s:  after: d = {d.lo, s.lo}, s = {d.hi, s.hi}.
__device__ inline void plswapf(float& a, float& b) {
  asm("v_permlane32_swap_b32 %0, %1" : "+v"(a), "+v"(b));
}
__device__ inline void plswapu(unsigned int& a, unsigned int& b) {
  asm("v_permlane32_swap_b32 %0, %1" : "+v"(a), "+v"(b));
}
__device__ inline float hmax16(const f32x16& v) {
  float a0 = fmaxf(v[0], v[1]),   a1 = fmaxf(v[2], v[3]);
  float a2 = fmaxf(v[4], v[5]),   a3 = fmaxf(v[6], v[7]);
  float a4 = fmaxf(v[8], v[9]),   a5 = fmaxf(v[10], v[11]);
  float a6 = fmaxf(v[12], v[13]), a7 = fmaxf(v[14], v[15]);
  float b0 = fmaxf(a0, a1), b1 = fmaxf(a2, a3);
  float b2 = fmaxf(a4, a5), b3 = fmaxf(a6, a7);
  return fmaxf(fmaxf(b0, b1), fmaxf(b2, b3));
}
__device__ inline float hsum16(const f32x16& v) {
  float a0 = v[0]+v[1],   a1 = v[2]+v[3],   a2 = v[4]+v[5],   a3 = v[6]+v[7];
  float a4 = v[8]+v[9],   a5 = v[10]+v[11], a6 = v[12]+v[13], a7 = v[14]+v[15];
  float b0 = a0+a1, b1 = a2+a3, b2 = a4+a5, b3 = a6+a7;
  return (b0+b1)+(b2+b3);
}

// ---------------- fp32 -> bf16 (vectorized) --------------------------------
__global__ __launch_bounds__(256) void f2b_kernel(const float* __restrict__ in,
                                                  bf16* __restrict__ out, int n4) {
  int i = blockIdx.x * 256 + threadIdx.x;
  if (i >= n4) return;
  float4 v = ((const float4*)in)[i];
  ushort4 o;
  o.x = f2bfbits(v.x); o.y = f2bfbits(v.y); o.z = f2bfbits(v.z); o.w = f2bfbits(v.w);
  ((ushort4*)out)[i] = o;
}

// ---------------- fp32 [R][Cc] -> bf16 transpose [Cc][R] -------------------
__global__ __launch_bounds__(256) void transpose_f2b(const float* __restrict__ in,
                                                     bf16* __restrict__ out,
                                                     int R, int Cc) {
  __shared__ float tile[32][33];
  int tx = threadIdx.x, ty = threadIdx.y;
  int bx = blockIdx.x, by = blockIdx.y;
  int col = bx * 32 + tx;
#pragma unroll
  for (int i = 0; i < 4; ++i) {
    int row = by * 32 + ty + i * 8;
    tile[ty + i * 8][tx] = in[(size_t)row * Cc + col];
  }
  __syncthreads();
#pragma unroll
  for (int i = 0; i < 4; ++i) {
    int orow = bx * 32 + ty + i * 8;   // original col
    int ocol = by * 32 + tx;           // original row
    out[(size_t)orow * R + ocol] = __float2bfloat16(tile[tx][ty + i * 8]);
  }
}

// ---------------- GEMM: C[M][N] = A[M][K] * Bt[N][K]^T ---------------------
// 128x128 tile, BK=64, 4 waves (2x2), 4x4 16x16 frags per wave.
// Both-sides XOR swizzle: LDS[row][c] holds global chunk c^(row&7) (16B
// chunks, 128B rows) via inverse-swizzled global_load_lds source; ds_reads
// XOR the same pattern -> conflict-free. 1D grid with XCD swizzle (T1).
// MODE 2: fp32 row-major [M][N].  MODE 3: fused QKV epilogue (V^T via
// wave-private LDS transpose).
template <int MODE>
__global__ __launch_bounds__(256) void gemm_bf16(const bf16* __restrict__ A,
                                                 const bf16* __restrict__ Bt,
                                                 void* __restrict__ Cp,
                                                 int M, int N, int K) {
  __shared__ __align__(16) bf16 Al[128 * 64];   // 16 KB
  __shared__ __align__(16) bf16 Bl[128 * 64];   // 16 KB
  int tid = threadIdx.x;
  int w = tid >> 6, lane = tid & 63;
  int lr = lane & 15, lg = lane >> 4;
  // T1 XCD swizzle (grid % 8 == 0 for all our launches)
  int nmb = M >> 7;
  int wg = blockIdx.x;
  int chunk = (int)gridDim.x >> 3;
  int lin = (wg & 7) * chunk + (wg >> 3);
  int m0 = (lin % nmb) * 128;
  int n0 = (lin / nmb) * 128;
  int wr = w >> 1, wc = w & 1;
  f32x4 acc[4][4] = {};

  size_t Kb = (size_t)K * 2;
  int c8 = lane & 7, r8 = lane >> 3;           // src chunk, row-in-octet
  const char* Asrc = (const char*)A + (size_t)(m0 + w * 8 + r8) * Kb + ((c8 ^ r8) << 4);
  const char* Bsrc = (const char*)Bt + (size_t)(n0 + w * 8 + r8) * Kb + ((c8 ^ r8) << 4);
  char* Ald = (char*)Al + w * 1024;
  char* Bld = (char*)Bl + w * 1024;

  for (int kt = 0; kt < K; kt += 64) {
#pragma unroll
    for (int j = 0; j < 4; ++j) {              // rows j*32 + w*8 + r8
      GLOAD_LDS16(Asrc + (size_t)j * 32 * Kb + (size_t)kt * 2, Ald + j * 4096);
      GLOAD_LDS16(Bsrc + (size_t)j * 32 * Kb + (size_t)kt * 2, Bld + j * 4096);
    }
    __syncthreads();
#pragma unroll
    for (int kk = 0; kk < 2; ++kk) {
      short8 af[4], bfr[4];
#pragma unroll
      for (int f = 0; f < 4; ++f) {
        int ra = wr * 64 + f * 16 + lr;
        int rb = wc * 64 + f * 16 + lr;
        int cb = (((kk << 2) | lg) ^ (lr & 7)) << 4;
        af[f]  = *(const short8*)((const char*)Al + (size_t)ra * 128 + cb);
        bfr[f] = *(const short8*)((const char*)Bl + (size_t)rb * 128 + cb);
      }
#pragma unroll
      for (int i = 0; i < 4; ++i)
#pragma unroll
        for (int j = 0; j < 4; ++j)
          acc[i][j] = __builtin_amdgcn_mfma_f32_16x16x32_bf16(af[i], bfr[j], acc[i][j], 0, 0, 0);
    }
    __syncthreads();
  }

  bf16* Qb  = (bf16*)Cp;
  bf16* Kb2 = Qb + (size_t)Bd * NH * Td * HD;
  bf16* Vtb = Kb2 + (size_t)Bd * NKV * Td * HD;

  if (MODE == 3 && n0 >= 2560) {
    // ---- V^T epilogue: wave-private LDS transpose, coalesced stores ----
    // wave quadrant = 64 t-rows (m0+wr*64..) x 64 d-cols -> V^T[h][d][t]
    int h  = (n0 - 2560 + wc * 64) >> 6;
    int b  = m0 >> 11;
    int tg = (m0 & 2047) + wr * 64;
    char* tb = (w < 2 ? (char*)Al : (char*)Bl) + (w & 1) * 8192;
    // write [d][t'] bf16, swizzle byte ^= (d&7)<<4
#pragma unroll
    for (int i = 0; i < 4; ++i)
#pragma unroll
      for (int j = 0; j < 4; ++j)
#pragma unroll
        for (int r = 0; r < 4; r += 2) {
          int d  = j * 16 + lr;
          int tt = i * 16 + lg * 4 + r;
          unsigned int pk = pkbf(acc[i][j][r], acc[i][j][r + 1]);
          *(unsigned int*)(tb + (((size_t)d * 128 + tt * 2) ^ ((d & 7) << 4))) = pk;
        }
    asm volatile("s_waitcnt lgkmcnt(0)" ::: "memory");
    __builtin_amdgcn_sched_barrier(0);
    char* Vdst = (char*)Vtb + ((((size_t)b * NKV + h) * 64) * Td + tg) * 2;
#pragma unroll
    for (int p = 0; p < 8; ++p) {
      int d  = p * 8 + (lane >> 3);
      int tc = lane & 7;
      u32x4 v = *(const u32x4*)(tb + (((size_t)d * 128 + tc * 16) ^ ((d & 7) << 4)));
      *(u32x4*)(Vdst + (size_t)d * Td * 2 + tc * 16) = v;
    }
    return;
  }

#pragma unroll
  for (int i = 0; i < 4; ++i) {
#pragma unroll
    for (int j = 0; j < 4; ++j) {
#pragma unroll
      for (int r = 0; r < 4; ++r) {
        int mrow = m0 + wr * 64 + i * 16 + lg * 4 + r;
        int ncol = n0 + wc * 64 + j * 16 + lr;
        float v = acc[i][j][r];
        if (MODE == 2) {
          ((float*)Cp)[(size_t)mrow * N + ncol] = v;
        } else {
          int b = mrow >> 11, t = mrow & 2047;
          if (n0 < 2048) {             // Q: [B][32][T][64]
            int h = ncol >> 6, d = ncol & 63;
            Qb[(((size_t)b * NH + h) * Td + t) * HD + d] = __float2bfloat16(v);
          } else {                     // K: [B][8][T][64]
            int cc = ncol - 2048;
            int h = cc >> 6, d = cc & 63;
            Kb2[(((size_t)b * NKV + h) * Td + t) * HD + d] = __float2bfloat16(v);
          }
        }
      }
    }
  }
}

// ---------------- RoPE (in-place, native trig; Q pre-scaled) ---------------
__global__ __launch_bounds__(256) void rope_kernel(bf16* __restrict__ Q,
                                                   bf16* __restrict__ K,
                                                   int qpairs, int total) {
  int i = blockIdx.x * 256 + threadIdx.x;
  if (i >= total) return;
  unsigned int* buf; int p; float sc;
  if (i < qpairs) { buf = (unsigned int*)Q; p = i; sc = 0.18033688011112042f; } // 0.125*log2e
  else            { buf = (unsigned int*)K; p = i - qpairs; sc = 1.0f; }
  int d2 = p & 31;             // pair index within head dim (D/2 = 32)
  int t  = (p >> 5) & (Td - 1);
  unsigned int packed = buf[p];
  float xe = bf2f((unsigned short)(packed & 0xffffu));
  float xo = bf2f((unsigned short)(packed >> 16));
  // inv_freq = 10000^(-d2/32) = exp2(-d2 * log2(10000)/32)
  float inv = __builtin_amdgcn_exp2f((float)d2 * (-13.287712379549449f / 32.0f));
  float ang = (float)t * inv;
  float rev = ang * 0.15915494309189535f;     // radians -> revolutions
  rev = rev - floorf(rev);
  float s = __builtin_amdgcn_sinf(rev);
  float c = __builtin_amdgcn_cosf(rev);
  float re = (xe * c - xo * s) * sc;
  float ro = (xo * c + xe * s) * sc;
  buf[p] = (unsigned int)f2bfbits(re) | ((unsigned int)f2bfbits(ro) << 16);
}

// ---------------- Flash attention (causal, GQA), LDS-staged KV -------------
// grid (B*NH=64, 8 qb), 512 thr = 8 waves; wave w owns q rows qb*256+w*32..+31.
// LPT: qb = 7 - blockIdx.y (heavy blocks first).
// Per kv tile (64x64): wave w stages K rows [w*8,w*8+8) and Vt rows [w*8,+8)
// via ONE global_load_lds dwordx4 each (coalesced), with inverse-XOR-swizzled
// global source so XOR-swizzled ds_reads (byte ^= (row&7)<<4) are linear.
// 2-phase double buffer: STAGE(next) -> compute(cur) -> vmcnt(0)+barrier.
// Softmax: swapped QK^T (S^T col=q=lane&31), in-register, T12 pack, T13 defer.
__global__ __launch_bounds__(512, 4) void attn_kernel(const bf16* __restrict__ Q,
                                                      const bf16* __restrict__ K,
                                                      const bf16* __restrict__ Vt,
                                                      bf16* __restrict__ Y) {
  __shared__ __align__(16) char lds[2 * 16384];   // [buf][K 8KB | V 8KB]
  int tid = threadIdx.x, w = tid >> 6, lane = tid & 63;
  int lq = lane & 31;          // q column (and kv/d row within subtile)
  int H  = lane >> 5;          // lane half
  int qb = 7 - (int)blockIdx.y;
  int bh = blockIdx.x;
  int b = bh >> 5, h = bh & 31, kvh = h >> 2;
  int q0w = qb * 256 + w * 32;
  int qg  = q0w + lq;
  int tmax = qb * 4 + (w >> 1);    // this wave's last compute tile
  int Nt   = qb * 4 + 4;           // tiles staged by the block

  const bf16* Qp = Q + (((size_t)b * NH + h) * Td) * HD;
  const char* Kg = (const char*)(K + (((size_t)b * NKV + kvh) * Td) * HD);   // rows 128B
  const char* Vg = (const char*)(Vt + (((size_t)b * NKV + kvh) * HD) * Td);  // rows 4096B

  // Q B-fragments (pre-scaled in rope): qf[ck][j] = Q[qg][ck*16+H*8+j]
  short8 qf[4];
#pragma unroll
  for (int ck = 0; ck < 4; ++ck)
    qf[ck] = *(const short8*)(Qp + (size_t)qg * HD + ck * 16 + H * 8);

  // staging geometry: wave w stages tile rows [w*8, w*8+8), 16B per lane
  int srow   = lane >> 3;                       // 0..7 within the 8-row slab
  int scol16 = ((lane & 7) ^ srow) << 4;        // inverse-swizzled byte col
  const char* Ksrc0 = Kg + (size_t)(w * 8 + srow) * 128 + scol16;
  const char* Vsrc0 = Vg + (size_t)(w * 8 + srow) * 4096 + scol16;
  char* KldsW[2] = { lds + w * 1024,          lds + 16384 + w * 1024 };
  char* VldsW[2] = { lds + 8192 + w * 1024,   lds + 24576 + w * 1024 };

#define STAGE_KV(tt, bb) do {                                                 \
    GLOAD_LDS16(Ksrc0 + (size_t)(tt) * 64 * 128, KldsW[bb]);                  \
    GLOAD_LDS16(Vsrc0 + (size_t)(tt) * 128,      VldsW[bb]);                  \
  } while (0)

  f32x16 acc0 = {}, acc1 = {};     // O^T[d][q], d 0..31 / 32..63
  float m = -3e38f, l = 0.0f;
  int swz = (lq & 7) << 4;
  int rb0 = lq * 128, rb1 = (32 + lq) * 128;

  STAGE_KV(0, 0);
  asm volatile("s_waitcnt vmcnt(0)" ::: "memory");
  __syncthreads();

  for (int t = 0; t < Nt; ++t) {
    int cur = t & 1;
    if (t + 1 < Nt) STAGE_KV(t + 1, cur ^ 1);
    if (t <= tmax) {
      const char* Kl = lds + cur * 16384;
      const char* Vl = Kl + 8192;
      // ---- S^T = K . Q^T ----
      f32x16 s0 = {}, s1 = {};
      __builtin_amdgcn_s_setprio(1);
#pragma unroll
      for (int ck = 0; ck < 4; ++ck) {
        int c = (H * 16 + ck * 32) ^ swz;
        short8 kf0 = *(const short8*)(Kl + rb0 + c);
        short8 kf1 = *(const short8*)(Kl + rb1 + c);
        s0 = MFMA32(kf0, qf[ck], s0);
        s1 = MFMA32(kf1, qf[ck], s1);
      }
      __builtin_amdgcn_s_setprio(0);
      // ---- causal mask (diagonal tile only) ----
      if (t == tmax) {
        int kvb = t * 64;
#pragma unroll
        for (int rr = 0; rr < 16; ++rr) {
          int krel = (rr & 3) + 8 * (rr >> 2) + 4 * H;
          if (kvb + krel > qg)      s0[rr] = -3e38f;
          if (kvb + 32 + krel > qg) s1[rr] = -3e38f;
        }
      }
      // ---- row max (register tree + cross-half permlane swap) ----
      float mx = fmaxf(hmax16(s0), hmax16(s1));
      {
        float mb = mx;
        asm("" : "+v"(mb));
        plswapf(mx, mb);
        mx = fmaxf(mx, mb);
      }
      // ---- defer-rescale (T13, THR=8 in log2 domain) ----
      if (__any(mx > m + 8.0f)) {
        float mn = fmaxf(m, mx);
        float al = __builtin_amdgcn_exp2f(m - mn);
        m = mn;
        l *= al;
#pragma unroll
        for (int rr = 0; rr < 16; ++rr) { acc0[rr] *= al; acc1[rr] *= al; }
      }
      // ---- p = exp2(s - m) ----
#pragma unroll
      for (int rr = 0; rr < 16; ++rr) {
        s0[rr] = __builtin_amdgcn_exp2f(s0[rr] - m);
        s1[rr] = __builtin_amdgcn_exp2f(s1[rr] - m);
      }
      float ps = hsum16(s0) + hsum16(s1);
      {
        float pb = ps;
        asm("" : "+v"(pb));
        plswapf(ps, pb);
        ps += pb;
      }
      l += ps;
      // ---- pack P -> bf16 B-fragments (T12: cvt_pk + permlane32_swap) ----
      short8 pf[4];
#pragma unroll
      for (int tt = 0; tt < 2; ++tt) {
        const f32x16& sv = tt ? s1 : s0;
#pragma unroll
        for (int a2 = 0; a2 < 2; ++a2) {
          unsigned int A0 = pkbf(sv[8*a2 + 0], sv[8*a2 + 1]);
          unsigned int A1 = pkbf(sv[8*a2 + 2], sv[8*a2 + 3]);
          unsigned int B0 = pkbf(sv[8*a2 + 4], sv[8*a2 + 5]);
          unsigned int B1 = pkbf(sv[8*a2 + 6], sv[8*a2 + 7]);
          plswapu(A0, B0);
          plswapu(A1, B1);
          u32x4 t4;
          t4[0] = A0; t4[1] = A1; t4[2] = B0; t4[3] = B1;
          pf[2*tt + a2] = __builtin_bit_cast(short8, t4);
        }
      }
      // ---- O^T += V^T . P ----
      __builtin_amdgcn_s_setprio(1);
#pragma unroll
      for (int ks = 0; ks < 4; ++ks) {
        int c = (H * 16 + ks * 32) ^ swz;
        short8 vf0 = *(const short8*)(Vl + rb0 + c);
        short8 vf1 = *(const short8*)(Vl + rb1 + c);
        acc0 = MFMA32(vf0, pf[ks], acc0);
        acc1 = MFMA32(vf1, pf[ks], acc1);
      }
      __builtin_amdgcn_s_setprio(0);
    }
    asm volatile("s_waitcnt vmcnt(0)" ::: "memory");
    __syncthreads();
  }
#undef STAGE_KV

  // ---- epilogue: normalize, write Y[M][C] ----
  float rn = 1.0f / l;
  bf16* Yp = Y + ((size_t)b * Td + qg) * Cd + h * HD;
#pragma unroll
  for (int rr = 0; rr < 16; rr += 2) {
    int d = (rr & 3) + 8 * (rr >> 2) + 4 * H;   // d, d+1 for rr, rr+1
    unsigned int w0 = pkbf(acc0[rr] * rn, acc0[rr + 1] * rn);
    unsigned int w1 = pkbf(acc1[rr] * rn, acc1[rr + 1] * rn);
    *(unsigned int*)(Yp + d)      = w0;
    *(unsigned int*)(Yp + 32 + d) = w1;
  }
}

// ---------------------------------------------------------------------------
extern "C" void kernel_launch(void* const* d_in, const int* in_sizes, int n_in,
                              void* d_out, int out_size, void* d_ws, size_t ws_size,
                              hipStream_t stream) {
  const float* x  = (const float*)d_in[0];
  const float* wq = (const float*)d_in[1];
  const float* wk = (const float*)d_in[2];
  const float* wv = (const float*)d_in[3];
  const float* wo = (const float*)d_in[4];

  char* ws = (char*)d_ws;
  const size_t o_xb = 0;                                   // 16.78 MB (reused as yb)
  const size_t o_w1 = o_xb + (size_t)Md * Cd * 2;          // 12.58 MB (wqkvT / later woT)
  const size_t o_Q  = o_w1 + (size_t)3072 * Cd * 2;        // 16.78 MB
  const size_t o_K  = o_Q + (size_t)Bd * NH * Td * HD * 2; // 4.19 MB
  const size_t o_V  = o_K + (size_t)Bd * NKV * Td * HD * 2;// 4.19 MB

  bf16* xb  = (bf16*)(ws + o_xb);
  bf16* w1  = (bf16*)(ws + o_w1);
  bf16* Qb  = (bf16*)(ws + o_Q);
  bf16* Kb  = (bf16*)(ws + o_K);
  bf16* Vtb = (bf16*)(ws + o_V);
  bf16* yb  = xb;   // alias: x_bf16 dead after QKV GEMM

  // 1. x -> bf16
  {
    int n4 = (Md * Cd) / 4;
    f2b_kernel<<<dim3((n4 + 255) / 256), dim3(256), 0, stream>>>(x, xb, n4);
  }
  // 2. weight transposes (fp32 -> bf16^T) into one [3072][2048] buffer
  transpose_f2b<<<dim3(Cd / 32, Cd / 32), dim3(32, 8), 0, stream>>>(wq, w1, Cd, Cd);
  transpose_f2b<<<dim3(512 / 32, Cd / 32), dim3(32, 8), 0, stream>>>(wk, w1 + (size_t)2048 * Cd, Cd, 512);
  transpose_f2b<<<dim3(512 / 32, Cd / 32), dim3(32, 8), 0, stream>>>(wv, w1 + (size_t)2560 * Cd, Cd, 512);
  // 3. fused QKV projection (N = 3072), 1D grid + XCD swizzle
  gemm_bf16<3><<<dim3((Md / 128) * (3072 / 128)), dim3(256), 0, stream>>>(xb, w1, Qb, Md, 3072, Cd);
  // 4. wo transpose into w1 (wqkvT dead after GEMM)
  transpose_f2b<<<dim3(Cd / 32, Cd / 32), dim3(32, 8), 0, stream>>>(wo, w1, Cd, Cd);
  // 5. RoPE on Q and K (in place; Q pre-scaled by 0.125*log2e)
  {
    int qpairs = Bd * NH * Td * HD / 2;
    int kpairs = Bd * NKV * Td * HD / 2;
    int total = qpairs + kpairs;
    rope_kernel<<<dim3((total + 255) / 256), dim3(256), 0, stream>>>(Qb, Kb, qpairs, total);
  }
  // 6. attention -> yb (bf16 [M][C]); 8-wave LDS-staged blocks, LPT order
  attn_kernel<<<dim3(Bd * NH, 8), dim3(512), 0, stream>>>(Qb, Kb, Vtb, yb);
  // 7. output projection -> d_out (fp32), 1D grid + XCD swizzle
  gemm_bf16<2><<<dim3((Md / 128) * (Cd / 128)), dim3(256), 0, stream>>>(yb, w1, d_out, Md, Cd, Cd);
}

// Round 7
// 216.252 us; speedup vs baseline: 1.4049x; 1.0587x over previous
//
#include <hip/hip_runtime.h>
#include <hip/hip_bf16.h>
#include <cstdint>
#include <cstddef>

// ---------------------------------------------------------------------------
// LlamaAttention forward: out = Attn(RoPE(x@wq), RoPE(x@wk), x@wv) @ wo
// B=2 T=2048 C=2048 NH=32 NKV=8 D=64, causal, GQA rep=4, scale=1/8.
// R7: revert GEMM block mapping to natural 2D grid (R6's XCD linearization
// tripled FETCH_SIZE: 57->137MB); keep BK=64 conflict-free swizzle + V^T
// LDS-transpose epilogue. Fuse prep kernels: prep1 = x->bf16 + wq/wk/wv
// transposes, prep2 = wo transpose + RoPE (9 launches -> 5).
// ---------------------------------------------------------------------------

using bf16 = __hip_bfloat16;
using f32x4  = __attribute__((ext_vector_type(4))) float;
using f32x16 = __attribute__((ext_vector_type(16))) float;
using short8 = __attribute__((ext_vector_type(8))) short;
using u32x4  = __attribute__((ext_vector_type(4))) unsigned int;

typedef __attribute__((address_space(1))) const void* gp1_t;
typedef __attribute__((address_space(3))) void*       lp3_t;

#define GLOAD_LDS16(g, l)                                                     \
  __builtin_amdgcn_global_load_lds((gp1_t)(const void*)(g), (lp3_t)(void*)(l), 16, 0, 0)

#define MFMA32(a, b, c) __builtin_amdgcn_mfma_f32_32x32x16_bf16(a, b, c, 0, 0, 0)

static constexpr int Bd  = 2;
static constexpr int Td  = 2048;
static constexpr int Cd  = 2048;
static constexpr int NH  = 32;
static constexpr int NKV = 8;
static constexpr int HD  = 64;
static constexpr int Md  = Bd * Td;     // 4096 rows

__device__ inline float bf2f(unsigned short u) {
  union { unsigned int i; float f; } v; v.i = ((unsigned int)u) << 16; return v.f;
}
__device__ inline unsigned short f2bfbits(float f) {
  union { float f; unsigned int u; } v; v.f = f;
  unsigned int r = v.u + 0x7fffu + ((v.u >> 16) & 1u);   // RNE
  return (unsigned short)(r >> 16);
}
__device__ inline unsigned int pkbf(float a, float b) {   // lo=bf16(a), hi=bf16(b)
  unsigned int r;
  asm("v_cvt_pk_bf16_f32 %0, %1, %2" : "=v"(r) : "v"(a), "v"(b));
  return r;
}
// v_permlane32_swap_b32 d, s:  after: d = {d.lo, s.lo}, s = {d.hi, s.hi}.
__device__ inline void plswapf(float& a, float& b) {
  asm("v_permlane32_swap_b32 %0, %1" : "+v"(a), "+v"(b));
}
__device__ inline void plswapu(unsigned int& a, unsigned int& b) {
  asm("v_permlane32_swap_b32 %0, %1" : "+v"(a), "+v"(b));
}
__device__ inline float hmax16(const f32x16& v) {
  float a0 = fmaxf(v[0], v[1]),   a1 = fmaxf(v[2], v[3]);
  float a2 = fmaxf(v[4], v[5]),   a3 = fmaxf(v[6], v[7]);
  float a4 = fmaxf(v[8], v[9]),   a5 = fmaxf(v[10], v[11]);
  float a6 = fmaxf(v[12], v[13]), a7 = fmaxf(v[14], v[15]);
  float b0 = fmaxf(a0, a1), b1 = fmaxf(a2, a3);
  float b2 = fmaxf(a4, a5), b3 = fmaxf(a6, a7);
  return fmaxf(fmaxf(b0, b1), fmaxf(b2, b3));
}
__device__ inline float hsum16(const f32x16& v) {
  float a0 = v[0]+v[1],   a1 = v[2]+v[3],   a2 = v[4]+v[5],   a3 = v[6]+v[7];
  float a4 = v[8]+v[9],   a5 = v[10]+v[11], a6 = v[12]+v[13], a7 = v[14]+v[15];
  float b0 = a0+a1, b1 = a2+a3, b2 = a4+a5, b3 = a6+a7;
  return (b0+b1)+(b2+b3);
}

// ---------------- prep1: x->bf16 + wq/wk/wv fp32->bf16^T -------------------
// blocks [0,8192): f2b of x (float4/thread).
// [8192,12288): wq^T (64x64 tiles); [12288,13312): wk^T; [13312,14336): wv^T.
__global__ __launch_bounds__(256) void prep1_kernel(const float* __restrict__ x,
                                                    const float* __restrict__ wq,
                                                    const float* __restrict__ wk,
                                                    const float* __restrict__ wv,
                                                    bf16* __restrict__ xb,
                                                    bf16* __restrict__ w1) {
  __shared__ float tile[32][33];
  int bid = blockIdx.x, tid = threadIdx.x;
  if (bid < 8192) {
    int i = bid * 256 + tid;
    float4 v = ((const float4*)x)[i];
    ushort4 o;
    o.x = f2bfbits(v.x); o.y = f2bfbits(v.y); o.z = f2bfbits(v.z); o.w = f2bfbits(v.w);
    ((ushort4*)xb)[i] = o;
    return;
  }
  const float* in; bf16* out; int Cc, bx, by;
  if (bid < 12288)      { int l = bid - 8192;  in = wq; out = w1;                        Cc = 2048; bx = l & 63; by = l >> 6; }
  else if (bid < 13312) { int l = bid - 12288; in = wk; out = w1 + (size_t)2048 * 2048;  Cc = 512;  bx = l & 15; by = l >> 4; }
  else                  { int l = bid - 13312; in = wv; out = w1 + (size_t)2560 * 2048;  Cc = 512;  bx = l & 15; by = l >> 4; }
  int tx = tid & 31, ty = tid >> 5;
  int col = bx * 32 + tx;
#pragma unroll
  for (int i = 0; i < 4; ++i) {
    int row = by * 32 + ty + i * 8;
    tile[ty + i * 8][tx] = in[(size_t)row * Cc + col];
  }
  __syncthreads();
#pragma unroll
  for (int i = 0; i < 4; ++i) {
    int orow = bx * 32 + ty + i * 8;
    int ocol = by * 32 + tx;
    out[(size_t)orow * 2048 + ocol] = __float2bfloat16(tile[tx][ty + i * 8]);
  }
}

// ---------------- prep2: wo^T + RoPE (Q pre-scaled) ------------------------
// blocks [0,4096): wo transpose -> w1; [4096, 4096+20480): rope on Q|K.
__global__ __launch_bounds__(256) void prep2_kernel(const float* __restrict__ wo,
                                                    bf16* __restrict__ w1,
                                                    bf16* __restrict__ Q,
                                                    bf16* __restrict__ K,
                                                    int qpairs, int total) {
  __shared__ float tile[32][33];
  int bid = blockIdx.x, tid = threadIdx.x;
  if (bid < 4096) {
    int bx = bid & 63, by = bid >> 6;
    int tx = tid & 31, ty = tid >> 5;
    int col = bx * 32 + tx;
#pragma unroll
    for (int i = 0; i < 4; ++i) {
      int row = by * 32 + ty + i * 8;
      tile[ty + i * 8][tx] = wo[(size_t)row * 2048 + col];
    }
    __syncthreads();
#pragma unroll
    for (int i = 0; i < 4; ++i) {
      int orow = bx * 32 + ty + i * 8;
      int ocol = by * 32 + tx;
      w1[(size_t)orow * 2048 + ocol] = __float2bfloat16(tile[tx][ty + i * 8]);
    }
    return;
  }
  int i = (bid - 4096) * 256 + tid;
  if (i >= total) return;
  unsigned int* buf; int p; float sc;
  if (i < qpairs) { buf = (unsigned int*)Q; p = i; sc = 0.18033688011112042f; } // 0.125*log2e
  else            { buf = (unsigned int*)K; p = i - qpairs; sc = 1.0f; }
  int d2 = p & 31;
  int t  = (p >> 5) & (Td - 1);
  unsigned int packed = buf[p];
  float xe = bf2f((unsigned short)(packed & 0xffffu));
  float xo = bf2f((unsigned short)(packed >> 16));
  float inv = __builtin_amdgcn_exp2f((float)d2 * (-13.287712379549449f / 32.0f));
  float ang = (float)t * inv;
  float rev = ang * 0.15915494309189535f;
  rev = rev - floorf(rev);
  float s = __builtin_amdgcn_sinf(rev);
  float c = __builtin_amdgcn_cosf(rev);
  float re = (xe * c - xo * s) * sc;
  float ro = (xo * c + xe * s) * sc;
  buf[p] = (unsigned int)f2bfbits(re) | ((unsigned int)f2bfbits(ro) << 16);
}

// ---------------- GEMM: C[M][N] = A[M][K] * Bt[N][K]^T ---------------------
// 128x128 tile, BK=64, 4 waves (2x2), 4x4 16x16 frags per wave. Natural 2D
// grid (m0=bx, n0=by — best measured L2 locality). Both-sides XOR swizzle:
// LDS[row][c] holds global chunk c^(row&7) (16B chunks, 128B rows) via
// inverse-swizzled global_load_lds source; ds_reads XOR the same pattern.
// MODE 2: fp32 row-major [M][N].  MODE 3: fused QKV epilogue (V^T via
// wave-private LDS transpose).
template <int MODE>
__global__ __launch_bounds__(256) void gemm_bf16(const bf16* __restrict__ A,
                                                 const bf16* __restrict__ Bt,
                                                 void* __restrict__ Cp,
                                                 int M, int N, int K) {
  __shared__ __align__(16) bf16 Al[128 * 64];   // 16 KB
  __shared__ __align__(16) bf16 Bl[128 * 64];   // 16 KB
  int tid = threadIdx.x;
  int w = tid >> 6, lane = tid & 63;
  int lr = lane & 15, lg = lane >> 4;
  int m0 = blockIdx.x * 128, n0 = blockIdx.y * 128;
  int wr = w >> 1, wc = w & 1;
  f32x4 acc[4][4] = {};

  size_t Kb = (size_t)K * 2;
  int c8 = lane & 7, r8 = lane >> 3;           // src chunk, row-in-octet
  const char* Asrc = (const char*)A + (size_t)(m0 + w * 8 + r8) * Kb + ((c8 ^ r8) << 4);
  const char* Bsrc = (const char*)Bt + (size_t)(n0 + w * 8 + r8) * Kb + ((c8 ^ r8) << 4);
  char* Ald = (char*)Al + w * 1024;
  char* Bld = (char*)Bl + w * 1024;

  for (int kt = 0; kt < K; kt += 64) {
#pragma unroll
    for (int j = 0; j < 4; ++j) {              // rows j*32 + w*8 + r8
      GLOAD_LDS16(Asrc + (size_t)j * 32 * Kb + (size_t)kt * 2, Ald + j * 4096);
      GLOAD_LDS16(Bsrc + (size_t)j * 32 * Kb + (size_t)kt * 2, Bld + j * 4096);
    }
    __syncthreads();
#pragma unroll
    for (int kk = 0; kk < 2; ++kk) {
      short8 af[4], bfr[4];
#pragma unroll
      for (int f = 0; f < 4; ++f) {
        int ra = wr * 64 + f * 16 + lr;
        int rb = wc * 64 + f * 16 + lr;
        int cb = (((kk << 2) | lg) ^ (lr & 7)) << 4;
        af[f]  = *(const short8*)((const char*)Al + (size_t)ra * 128 + cb);
        bfr[f] = *(const short8*)((const char*)Bl + (size_t)rb * 128 + cb);
      }
#pragma unroll
      for (int i = 0; i < 4; ++i)
#pragma unroll
        for (int j = 0; j < 4; ++j)
          acc[i][j] = __builtin_amdgcn_mfma_f32_16x16x32_bf16(af[i], bfr[j], acc[i][j], 0, 0, 0);
    }
    __syncthreads();
  }

  bf16* Qb  = (bf16*)Cp;
  bf16* Kb2 = Qb + (size_t)Bd * NH * Td * HD;
  bf16* Vtb = Kb2 + (size_t)Bd * NKV * Td * HD;

  if (MODE == 3 && n0 >= 2560) {
    // ---- V^T epilogue: wave-private LDS transpose, coalesced stores ----
    int h  = (n0 - 2560 + wc * 64) >> 6;
    int b  = m0 >> 11;
    int tg = (m0 & 2047) + wr * 64;
    char* tb = (w < 2 ? (char*)Al : (char*)Bl) + (w & 1) * 8192;
#pragma unroll
    for (int i = 0; i < 4; ++i)
#pragma unroll
      for (int j = 0; j < 4; ++j)
#pragma unroll
        for (int r = 0; r < 4; r += 2) {
          int d  = j * 16 + lr;
          int tt = i * 16 + lg * 4 + r;
          unsigned int pk = pkbf(acc[i][j][r], acc[i][j][r + 1]);
          *(unsigned int*)(tb + (((size_t)d * 128 + tt * 2) ^ ((d & 7) << 4))) = pk;
        }
    asm volatile("s_waitcnt lgkmcnt(0)" ::: "memory");
    __builtin_amdgcn_sched_barrier(0);
    char* Vdst = (char*)Vtb + ((((size_t)b * NKV + h) * 64) * Td + tg) * 2;
#pragma unroll
    for (int p = 0; p < 8; ++p) {
      int d  = p * 8 + (lane >> 3);
      int tc = lane & 7;
      u32x4 v = *(const u32x4*)(tb + (((size_t)d * 128 + tc * 16) ^ ((d & 7) << 4)));
      *(u32x4*)(Vdst + (size_t)d * Td * 2 + tc * 16) = v;
    }
    return;
  }

#pragma unroll
  for (int i = 0; i < 4; ++i) {
#pragma unroll
    for (int j = 0; j < 4; ++j) {
#pragma unroll
      for (int r = 0; r < 4; ++r) {
        int mrow = m0 + wr * 64 + i * 16 + lg * 4 + r;
        int ncol = n0 + wc * 64 + j * 16 + lr;
        float v = acc[i][j][r];
        if (MODE == 2) {
          ((float*)Cp)[(size_t)mrow * N + ncol] = v;
        } else {
          int b = mrow >> 11, t = mrow & 2047;
          if (n0 < 2048) {             // Q: [B][32][T][64]
            int h = ncol >> 6, d = ncol & 63;
            Qb[(((size_t)b * NH + h) * Td + t) * HD + d] = __float2bfloat16(v);
          } else {                     // K: [B][8][T][64]
            int cc = ncol - 2048;
            int h = cc >> 6, d = cc & 63;
            Kb2[(((size_t)b * NKV + h) * Td + t) * HD + d] = __float2bfloat16(v);
          }
        }
      }
    }
  }
}

// ---------------- Flash attention (causal, GQA), LDS-staged KV -------------
// grid (B*NH=64, 8 qb), 512 thr = 8 waves; wave w owns q rows qb*256+w*32..+31.
// LPT: qb = 7 - blockIdx.y (heavy blocks first).
// Per kv tile (64x64): wave w stages K rows [w*8,w*8+8) and Vt rows [w*8,+8)
// via ONE global_load_lds dwordx4 each (coalesced), with inverse-XOR-swizzled
// global source so XOR-swizzled ds_reads (byte ^= (row&7)<<4) are linear.
// 2-phase double buffer: STAGE(next) -> compute(cur) -> vmcnt(0)+barrier.
// Softmax: swapped QK^T (S^T col=q=lane&31), in-register, T12 pack, T13 defer.
__global__ __launch_bounds__(512, 4) void attn_kernel(const bf16* __restrict__ Q,
                                                      const bf16* __restrict__ K,
                                                      const bf16* __restrict__ Vt,
                                                      bf16* __restrict__ Y) {
  __shared__ __align__(16) char lds[2 * 16384];   // [buf][K 8KB | V 8KB]
  int tid = threadIdx.x, w = tid >> 6, lane = tid & 63;
  int lq = lane & 31;          // q column (and kv/d row within subtile)
  int H  = lane >> 5;          // lane half
  int qb = 7 - (int)blockIdx.y;
  int bh = blockIdx.x;
  int b = bh >> 5, h = bh & 31, kvh = h >> 2;
  int q0w = qb * 256 + w * 32;
  int qg  = q0w + lq;
  int tmax = qb * 4 + (w >> 1);    // this wave's last compute tile
  int Nt   = qb * 4 + 4;           // tiles staged by the block

  const bf16* Qp = Q + (((size_t)b * NH + h) * Td) * HD;
  const char* Kg = (const char*)(K + (((size_t)b * NKV + kvh) * Td) * HD);   // rows 128B
  const char* Vg = (const char*)(Vt + (((size_t)b * NKV + kvh) * HD) * Td);  // rows 4096B

  // Q B-fragments (pre-scaled in rope): qf[ck][j] = Q[qg][ck*16+H*8+j]
  short8 qf[4];
#pragma unroll
  for (int ck = 0; ck < 4; ++ck)
    qf[ck] = *(const short8*)(Qp + (size_t)qg * HD + ck * 16 + H * 8);

  // staging geometry: wave w stages tile rows [w*8, w*8+8), 16B per lane
  int srow   = lane >> 3;                       // 0..7 within the 8-row slab
  int scol16 = ((lane & 7) ^ srow) << 4;        // inverse-swizzled byte col
  const char* Ksrc0 = Kg + (size_t)(w * 8 + srow) * 128 + scol16;
  const char* Vsrc0 = Vg + (size_t)(w * 8 + srow) * 4096 + scol16;
  char* KldsW[2] = { lds + w * 1024,          lds + 16384 + w * 1024 };
  char* VldsW[2] = { lds + 8192 + w * 1024,   lds + 24576 + w * 1024 };

#define STAGE_KV(tt, bb) do {                                                 \
    GLOAD_LDS16(Ksrc0 + (size_t)(tt) * 64 * 128, KldsW[bb]);                  \
    GLOAD_LDS16(Vsrc0 + (size_t)(tt) * 128,      VldsW[bb]);                  \
  } while (0)

  f32x16 acc0 = {}, acc1 = {};     // O^T[d][q], d 0..31 / 32..63
  float m = -3e38f, l = 0.0f;
  int swz = (lq & 7) << 4;
  int rb0 = lq * 128, rb1 = (32 + lq) * 128;

  STAGE_KV(0, 0);
  asm volatile("s_waitcnt vmcnt(0)" ::: "memory");
  __syncthreads();

  for (int t = 0; t < Nt; ++t) {
    int cur = t & 1;
    if (t + 1 < Nt) STAGE_KV(t + 1, cur ^ 1);
    if (t <= tmax) {
      const char* Kl = lds + cur * 16384;
      const char* Vl = Kl + 8192;
      // ---- S^T = K . Q^T ----
      f32x16 s0 = {}, s1 = {};
      __builtin_amdgcn_s_setprio(1);
#pragma unroll
      for (int ck = 0; ck < 4; ++ck) {
        int c = (H * 16 + ck * 32) ^ swz;
        short8 kf0 = *(const short8*)(Kl + rb0 + c);
        short8 kf1 = *(const short8*)(Kl + rb1 + c);
        s0 = MFMA32(kf0, qf[ck], s0);
        s1 = MFMA32(kf1, qf[ck], s1);
      }
      __builtin_amdgcn_s_setprio(0);
      // ---- causal mask (diagonal tile only) ----
      if (t == tmax) {
        int kvb = t * 64;
#pragma unroll
        for (int rr = 0; rr < 16; ++rr) {
          int krel = (rr & 3) + 8 * (rr >> 2) + 4 * H;
          if (kvb + krel > qg)      s0[rr] = -3e38f;
          if (kvb + 32 + krel > qg) s1[rr] = -3e38f;
        }
      }
      // ---- row max (register tree + cross-half permlane swap) ----
      float mx = fmaxf(hmax16(s0), hmax16(s1));
      {
        float mb = mx;
        asm("" : "+v"(mb));
        plswapf(mx, mb);
        mx = fmaxf(mx, mb);
      }
      // ---- defer-rescale (T13, THR=8 in log2 domain) ----
      if (__any(mx > m + 8.0f)) {
        float mn = fmaxf(m, mx);
        float al = __builtin_amdgcn_exp2f(m - mn);
        m = mn;
        l *= al;
#pragma unroll
        for (int rr = 0; rr < 16; ++rr) { acc0[rr] *= al; acc1[rr] *= al; }
      }
      // ---- p = exp2(s - m) ----
#pragma unroll
      for (int rr = 0; rr < 16; ++rr) {
        s0[rr] = __builtin_amdgcn_exp2f(s0[rr] - m);
        s1[rr] = __builtin_amdgcn_exp2f(s1[rr] - m);
      }
      float ps = hsum16(s0) + hsum16(s1);
      {
        float pb = ps;
        asm("" : "+v"(pb));
        plswapf(ps, pb);
        ps += pb;
      }
      l += ps;
      // ---- pack P -> bf16 B-fragments (T12: cvt_pk + permlane32_swap) ----
      short8 pf[4];
#pragma unroll
      for (int tt = 0; tt < 2; ++tt) {
        const f32x16& sv = tt ? s1 : s0;
#pragma unroll
        for (int a2 = 0; a2 < 2; ++a2) {
          unsigned int A0 = pkbf(sv[8*a2 + 0], sv[8*a2 + 1]);
          unsigned int A1 = pkbf(sv[8*a2 + 2], sv[8*a2 + 3]);
          unsigned int B0 = pkbf(sv[8*a2 + 4], sv[8*a2 + 5]);
          unsigned int B1 = pkbf(sv[8*a2 + 6], sv[8*a2 + 7]);
          plswapu(A0, B0);
          plswapu(A1, B1);
          u32x4 t4;
          t4[0] = A0; t4[1] = A1; t4[2] = B0; t4[3] = B1;
          pf[2*tt + a2] = __builtin_bit_cast(short8, t4);
        }
      }
      // ---- O^T += V^T . P ----
      __builtin_amdgcn_s_setprio(1);
#pragma unroll
      for (int ks = 0; ks < 4; ++ks) {
        int c = (H * 16 + ks * 32) ^ swz;
        short8 vf0 = *(const short8*)(Vl + rb0 + c);
        short8 vf1 = *(const short8*)(Vl + rb1 + c);
        acc0 = MFMA32(vf0, pf[ks], acc0);
        acc1 = MFMA32(vf1, pf[ks], acc1);
      }
      __builtin_amdgcn_s_setprio(0);
    }
    asm volatile("s_waitcnt vmcnt(0)" ::: "memory");
    __syncthreads();
  }
#undef STAGE_KV

  // ---- epilogue: normalize, write Y[M][C] ----
  float rn = 1.0f / l;
  bf16* Yp = Y + ((size_t)b * Td + qg) * Cd + h * HD;
#pragma unroll
  for (int rr = 0; rr < 16; rr += 2) {
    int d = (rr & 3) + 8 * (rr >> 2) + 4 * H;   // d, d+1 for rr, rr+1
    unsigned int w0 = pkbf(acc0[rr] * rn, acc0[rr + 1] * rn);
    unsigned int w1 = pkbf(acc1[rr] * rn, acc1[rr + 1] * rn);
    *(unsigned int*)(Yp + d)      = w0;
    *(unsigned int*)(Yp + 32 + d) = w1;
  }
}

// ---------------------------------------------------------------------------
extern "C" void kernel_launch(void* const* d_in, const int* in_sizes, int n_in,
                              void* d_out, int out_size, void* d_ws, size_t ws_size,
                              hipStream_t stream) {
  const float* x  = (const float*)d_in[0];
  const float* wq = (const float*)d_in[1];
  const float* wk = (const float*)d_in[2];
  const float* wv = (const float*)d_in[3];
  const float* wo = (const float*)d_in[4];

  char* ws = (char*)d_ws;
  const size_t o_xb = 0;                                   // 16.78 MB (reused as yb)
  const size_t o_w1 = o_xb + (size_t)Md * Cd * 2;          // 12.58 MB (wqkvT / later woT)
  const size_t o_Q  = o_w1 + (size_t)3072 * Cd * 2;        // 16.78 MB
  const size_t o_K  = o_Q + (size_t)Bd * NH * Td * HD * 2; // 4.19 MB
  const size_t o_V  = o_K + (size_t)Bd * NKV * Td * HD * 2;// 4.19 MB

  bf16* xb  = (bf16*)(ws + o_xb);
  bf16* w1  = (bf16*)(ws + o_w1);
  bf16* Qb  = (bf16*)(ws + o_Q);
  bf16* Kb  = (bf16*)(ws + o_K);
  bf16* Vtb = (bf16*)(ws + o_V);
  bf16* yb  = xb;   // alias: x_bf16 dead after QKV GEMM

  // 1. prep1: x->bf16 + wq/wk/wv transposes (one launch)
  prep1_kernel<<<dim3(14336), dim3(256), 0, stream>>>(x, wq, wk, wv, xb, w1);
  // 2. fused QKV projection (N = 3072), natural 2D grid
  gemm_bf16<3><<<dim3(Md / 128, 3072 / 128), dim3(256), 0, stream>>>(xb, w1, Qb, Md, 3072, Cd);
  // 3. prep2: wo transpose (w1 free) + RoPE on Q/K (one launch)
  {
    int qpairs = Bd * NH * Td * HD / 2;
    int kpairs = Bd * NKV * Td * HD / 2;
    int total = qpairs + kpairs;
    prep2_kernel<<<dim3(4096 + 20480), dim3(256), 0, stream>>>(wo, w1, Qb, Kb, qpairs, total);
  }
  // 4. attention -> yb (bf16 [M][C]); 8-wave LDS-staged blocks, LPT order
  attn_kernel<<<dim3(Bd * NH, 8), dim3(512), 0, stream>>>(Qb, Kb, Vtb, yb);
  // 5. output projection -> d_out (fp32), natural 2D grid
  gemm_bf16<2><<<dim3(Md / 128, Cd / 128), dim3(256), 0, stream>>>(yb, w1, d_out, Md, Cd, Cd);
}

// Round 8
// 198.335 us; speedup vs baseline: 1.5319x; 1.0903x over previous
//
#include <hip/hip_runtime.h>
#include <hip/hip_bf16.h>
#include <cstdint>
#include <cstddef>

// ---------------------------------------------------------------------------
// LlamaAttention forward: out = Attn(RoPE(x@wq), RoPE(x@wk), x@wv) @ wo
// B=2 T=2048 C=2048 NH=32 NKV=8 D=64, causal, GQA rep=4, scale=1/8.
// R8: GEMM -> 2-phase double-buffered pipeline (stage t+1 issued BEFORE
// compute t; one vmcnt(0)+barrier per K-tile — T3-minimum recipe). RoPE
// fused into the QKV epilogue (shfl_xor(1) lane-pair rotation, Q prescale
// folded); rope kernel deleted. prep2 = wo transpose only.
// ---------------------------------------------------------------------------

using bf16 = __hip_bfloat16;
using f32x4  = __attribute__((ext_vector_type(4))) float;
using f32x16 = __attribute__((ext_vector_type(16))) float;
using short8 = __attribute__((ext_vector_type(8))) short;
using u32x4  = __attribute__((ext_vector_type(4))) unsigned int;

typedef __attribute__((address_space(1))) const void* gp1_t;
typedef __attribute__((address_space(3))) void*       lp3_t;

#define GLOAD_LDS16(g, l)                                                     \
  __builtin_amdgcn_global_load_lds((gp1_t)(const void*)(g), (lp3_t)(void*)(l), 16, 0, 0)

#define MFMA32(a, b, c) __builtin_amdgcn_mfma_f32_32x32x16_bf16(a, b, c, 0, 0, 0)

static constexpr int Bd  = 2;
static constexpr int Td  = 2048;
static constexpr int Cd  = 2048;
static constexpr int NH  = 32;
static constexpr int NKV = 8;
static constexpr int HD  = 64;
static constexpr int Md  = Bd * Td;     // 4096 rows

__device__ inline float bf2f(unsigned short u) {
  union { unsigned int i; float f; } v; v.i = ((unsigned int)u) << 16; return v.f;
}
__device__ inline unsigned short f2bfbits(float f) {
  union { float f; unsigned int u; } v; v.f = f;
  unsigned int r = v.u + 0x7fffu + ((v.u >> 16) & 1u);   // RNE
  return (unsigned short)(r >> 16);
}
__device__ inline unsigned int pkbf(float a, float b) {   // lo=bf16(a), hi=bf16(b)
  unsigned int r;
  asm("v_cvt_pk_bf16_f32 %0, %1, %2" : "=v"(r) : "v"(a), "v"(b));
  return r;
}
// v_permlane32_swap_b32 d, s:  after: d = {d.lo, s.lo}, s = {d.hi, s.hi}.
__device__ inline void plswapf(float& a, float& b) {
  asm("v_permlane32_swap_b32 %0, %1" : "+v"(a), "+v"(b));
}
__device__ inline void plswapu(unsigned int& a, unsigned int& b) {
  asm("v_permlane32_swap_b32 %0, %1" : "+v"(a), "+v"(b));
}
__device__ inline float hmax16(const f32x16& v) {
  float a0 = fmaxf(v[0], v[1]),   a1 = fmaxf(v[2], v[3]);
  float a2 = fmaxf(v[4], v[5]),   a3 = fmaxf(v[6], v[7]);
  float a4 = fmaxf(v[8], v[9]),   a5 = fmaxf(v[10], v[11]);
  float a6 = fmaxf(v[12], v[13]), a7 = fmaxf(v[14], v[15]);
  float b0 = fmaxf(a0, a1), b1 = fmaxf(a2, a3);
  float b2 = fmaxf(a4, a5), b3 = fmaxf(a6, a7);
  return fmaxf(fmaxf(b0, b1), fmaxf(b2, b3));
}
__device__ inline float hsum16(const f32x16& v) {
  float a0 = v[0]+v[1],   a1 = v[2]+v[3],   a2 = v[4]+v[5],   a3 = v[6]+v[7];
  float a4 = v[8]+v[9],   a5 = v[10]+v[11], a6 = v[12]+v[13], a7 = v[14]+v[15];
  float b0 = a0+a1, b1 = a2+a3, b2 = a4+a5, b3 = a6+a7;
  return (b0+b1)+(b2+b3);
}

// ---------------- prep1: x->bf16 + wq/wk/wv fp32->bf16^T -------------------
// blocks [0,8192): f2b of x (float4/thread).
// [8192,12288): wq^T; [12288,13312): wk^T; [13312,14336): wv^T.
__global__ __launch_bounds__(256) void prep1_kernel(const float* __restrict__ x,
                                                    const float* __restrict__ wq,
                                                    const float* __restrict__ wk,
                                                    const float* __restrict__ wv,
                                                    bf16* __restrict__ xb,
                                                    bf16* __restrict__ w1) {
  __shared__ float tile[32][33];
  int bid = blockIdx.x, tid = threadIdx.x;
  if (bid < 8192) {
    int i = bid * 256 + tid;
    float4 v = ((const float4*)x)[i];
    ushort4 o;
    o.x = f2bfbits(v.x); o.y = f2bfbits(v.y); o.z = f2bfbits(v.z); o.w = f2bfbits(v.w);
    ((ushort4*)xb)[i] = o;
    return;
  }
  const float* in; bf16* out; int Cc, bx, by;
  if (bid < 12288)      { int l = bid - 8192;  in = wq; out = w1;                        Cc = 2048; bx = l & 63; by = l >> 6; }
  else if (bid < 13312) { int l = bid - 12288; in = wk; out = w1 + (size_t)2048 * 2048;  Cc = 512;  bx = l & 15; by = l >> 4; }
  else                  { int l = bid - 13312; in = wv; out = w1 + (size_t)2560 * 2048;  Cc = 512;  bx = l & 15; by = l >> 4; }
  int tx = tid & 31, ty = tid >> 5;
  int col = bx * 32 + tx;
#pragma unroll
  for (int i = 0; i < 4; ++i) {
    int row = by * 32 + ty + i * 8;
    tile[ty + i * 8][tx] = in[(size_t)row * Cc + col];
  }
  __syncthreads();
#pragma unroll
  for (int i = 0; i < 4; ++i) {
    int orow = bx * 32 + ty + i * 8;
    int ocol = by * 32 + tx;
    out[(size_t)orow * 2048 + ocol] = __float2bfloat16(tile[tx][ty + i * 8]);
  }
}

// ---------------- fp32 [R][Cc] -> bf16 transpose [Cc][R] (wo) --------------
__global__ __launch_bounds__(256) void transpose_f2b(const float* __restrict__ in,
                                                     bf16* __restrict__ out,
                                                     int R, int Cc) {
  __shared__ float tile[32][33];
  int tx = threadIdx.x & 31, ty = threadIdx.x >> 5;
  int bx = blockIdx.x, by = blockIdx.y;
  int col = bx * 32 + tx;
#pragma unroll
  for (int i = 0; i < 4; ++i) {
    int row = by * 32 + ty + i * 8;
    tile[ty + i * 8][tx] = in[(size_t)row * Cc + col];
  }
  __syncthreads();
#pragma unroll
  for (int i = 0; i < 4; ++i) {
    int orow = bx * 32 + ty + i * 8;
    int ocol = by * 32 + tx;
    out[(size_t)orow * R + ocol] = __float2bfloat16(tile[tx][ty + i * 8]);
  }
}

// ---------------- GEMM: C[M][N] = A[M][K] * Bt[N][K]^T ---------------------
// 128x128 tile, BK=64, 2-phase double-buffered LDS (64 KB): stage(t+1)
// issued BEFORE compute(t); one barrier (vmcnt0+lgkm0) per K-tile.
// Both-sides XOR swizzle (conflict-free ds_read_b128). Natural 2D grid.
// MODE 2: fp32 row-major [M][N].
// MODE 3: fused QKV epilogue — RoPE applied in-register to Q (prescaled) and
//         K via shfl_xor(1) lane pairing; V^T via wave-private LDS transpose.
template <int MODE>
__global__ __launch_bounds__(256, 2) void gemm_bf16(const bf16* __restrict__ A,
                                                    const bf16* __restrict__ Bt,
                                                    void* __restrict__ Cp,
                                                    int M, int N, int K) {
  __shared__ __align__(16) bf16 Al[2][128 * 64];   // 2 x 16 KB
  __shared__ __align__(16) bf16 Bl[2][128 * 64];   // 2 x 16 KB
  int tid = threadIdx.x;
  int w = tid >> 6, lane = tid & 63;
  int lr = lane & 15, lg = lane >> 4;
  int m0 = blockIdx.x * 128, n0 = blockIdx.y * 128;
  int wr = w >> 1, wc = w & 1;
  f32x4 acc[4][4] = {};

  size_t Kb = (size_t)K * 2;
  int c8 = lane & 7, r8 = lane >> 3;           // src chunk, row-in-octet
  const char* Asrc = (const char*)A + (size_t)(m0 + w * 8 + r8) * Kb + ((c8 ^ r8) << 4);
  const char* Bsrc = (const char*)Bt + (size_t)(n0 + w * 8 + r8) * Kb + ((c8 ^ r8) << 4);

#define GSTAGE(kt, bb) do {                                                   \
    char* ald = (char*)&Al[bb][0] + w * 1024;                                 \
    char* bld = (char*)&Bl[bb][0] + w * 1024;                                 \
    _Pragma("unroll")                                                         \
    for (int j = 0; j < 4; ++j) {                                             \
      GLOAD_LDS16(Asrc + (size_t)j * 32 * Kb + (size_t)(kt) * 2, ald + j * 4096); \
      GLOAD_LDS16(Bsrc + (size_t)j * 32 * Kb + (size_t)(kt) * 2, bld + j * 4096); \
    }                                                                         \
  } while (0)

  int nkt = K >> 6;
  GSTAGE(0, 0);
  __syncthreads();

  for (int t = 0; t < nkt; ++t) {
    int cur = t & 1;
    if (t + 1 < nkt) GSTAGE((t + 1) << 6, cur ^ 1);   // issue next-tile loads first
    const char* Ab = (const char*)&Al[cur][0];
    const char* Bb = (const char*)&Bl[cur][0];
#pragma unroll
    for (int kk = 0; kk < 2; ++kk) {
      short8 af[4], bfr[4];
#pragma unroll
      for (int f = 0; f < 4; ++f) {
        int ra = wr * 64 + f * 16 + lr;
        int rb = wc * 64 + f * 16 + lr;
        int cb = (((kk << 2) | lg) ^ (lr & 7)) << 4;
        af[f]  = *(const short8*)(Ab + (size_t)ra * 128 + cb);
        bfr[f] = *(const short8*)(Bb + (size_t)rb * 128 + cb);
      }
#pragma unroll
      for (int i = 0; i < 4; ++i)
#pragma unroll
        for (int j = 0; j < 4; ++j)
          acc[i][j] = __builtin_amdgcn_mfma_f32_16x16x32_bf16(af[i], bfr[j], acc[i][j], 0, 0, 0);
    }
    __syncthreads();   // drains next-tile loads (vmcnt0) + protects buffers
  }
#undef GSTAGE

  bf16* Qb  = (bf16*)Cp;
  bf16* Kb2 = Qb + (size_t)Bd * NH * Td * HD;
  bf16* Vtb = Kb2 + (size_t)Bd * NKV * Td * HD;

  if (MODE == 3 && n0 >= 2560) {
    // ---- V^T epilogue: wave-private LDS transpose, coalesced stores ----
    int h  = (n0 - 2560 + wc * 64) >> 6;
    int b  = m0 >> 11;
    int tg = (m0 & 2047) + wr * 64;
    char* tb = (w < 2 ? (char*)&Al[0][0] : (char*)&Bl[0][0]) + (w & 1) * 8192;
#pragma unroll
    for (int i = 0; i < 4; ++i)
#pragma unroll
      for (int j = 0; j < 4; ++j)
#pragma unroll
        for (int r = 0; r < 4; r += 2) {
          int d  = j * 16 + lr;
          int tt = i * 16 + lg * 4 + r;
          unsigned int pk = pkbf(acc[i][j][r], acc[i][j][r + 1]);
          *(unsigned int*)(tb + (((size_t)d * 128 + tt * 2) ^ ((d & 7) << 4))) = pk;
        }
    asm volatile("s_waitcnt lgkmcnt(0)" ::: "memory");
    __builtin_amdgcn_sched_barrier(0);
    char* Vdst = (char*)Vtb + ((((size_t)b * NKV + h) * 64) * Td + tg) * 2;
#pragma unroll
    for (int p = 0; p < 8; ++p) {
      int d  = p * 8 + (lane >> 3);
      int tc = lane & 7;
      u32x4 v = *(const u32x4*)(tb + (((size_t)d * 128 + tc * 16) ^ ((d & 7) << 4)));
      *(u32x4*)(Vdst + (size_t)d * Td * 2 + tc * 16) = v;
    }
    return;
  }

  if (MODE == 3) {
    // ---- Q/K epilogue with fused RoPE ----
    // d pairs (2k, 2k+1) live on adjacent lr lanes -> shfl_xor(v,1).
    const float RC = -0.41524101186092029f;        // -log2(10000)/32
    float sc = (n0 < 2048) ? 0.18033688011112042f : 1.0f;   // Q: 0.125*log2e
    int odd = lane & 1;
#pragma unroll
    for (int j = 0; j < 4; ++j) {
      int ncol = n0 + wc * 64 + j * 16 + lr;
      int d  = ncol & 63;
      float inv = __builtin_amdgcn_exp2f((float)(d >> 1) * RC);
#pragma unroll
      for (int i = 0; i < 4; ++i) {
#pragma unroll
        for (int r = 0; r < 4; ++r) {
          int mrow = m0 + wr * 64 + i * 16 + lg * 4 + r;
          int t = mrow & 2047;
          float v = acc[i][j][r];
          float p = __shfl_xor(v, 1);
          float rev = (float)t * inv * 0.15915494309189535f;
          rev = rev - floorf(rev);
          float s = __builtin_amdgcn_sinf(rev);
          float c = __builtin_amdgcn_cosf(rev);
          float res = odd ? (v * c + p * s) : (v * c - p * s);
          res *= sc;
          int b = mrow >> 11;
          if (n0 < 2048) {
            int h = ncol >> 6;
            Qb[(((size_t)b * NH + h) * Td + t) * HD + d] = __float2bfloat16(res);
          } else {
            int h = (ncol - 2048) >> 6;
            Kb2[(((size_t)b * NKV + h) * Td + t) * HD + d] = __float2bfloat16(res);
          }
        }
      }
    }
    return;
  }

#pragma unroll
  for (int i = 0; i < 4; ++i)
#pragma unroll
    for (int j = 0; j < 4; ++j)
#pragma unroll
      for (int r = 0; r < 4; ++r) {
        int mrow = m0 + wr * 64 + i * 16 + lg * 4 + r;
        int ncol = n0 + wc * 64 + j * 16 + lr;
        ((float*)Cp)[(size_t)mrow * N + ncol] = acc[i][j][r];
      }
}

// ---------------- Flash attention (causal, GQA), LDS-staged KV -------------
// grid (B*NH=64, 8 qb), 512 thr = 8 waves; wave w owns q rows qb*256+w*32..+31.
// LPT: qb = 7 - blockIdx.y (heavy blocks first).
// Per kv tile (64x64): wave w stages K rows [w*8,w*8+8) and Vt rows [w*8,+8)
// via ONE global_load_lds dwordx4 each (coalesced), with inverse-XOR-swizzled
// global source so XOR-swizzled ds_reads (byte ^= (row&7)<<4) are linear.
// 2-phase double buffer: STAGE(next) -> compute(cur) -> vmcnt(0)+barrier.
// Softmax: swapped QK^T (S^T col=q=lane&31), in-register, T12 pack, T13 defer.
__global__ __launch_bounds__(512, 4) void attn_kernel(const bf16* __restrict__ Q,
                                                      const bf16* __restrict__ K,
                                                      const bf16* __restrict__ Vt,
                                                      bf16* __restrict__ Y) {
  __shared__ __align__(16) char lds[2 * 16384];   // [buf][K 8KB | V 8KB]
  int tid = threadIdx.x, w = tid >> 6, lane = tid & 63;
  int lq = lane & 31;          // q column (and kv/d row within subtile)
  int H  = lane >> 5;          // lane half
  int qb = 7 - (int)blockIdx.y;
  int bh = blockIdx.x;
  int b = bh >> 5, h = bh & 31, kvh = h >> 2;
  int q0w = qb * 256 + w * 32;
  int qg  = q0w + lq;
  int tmax = qb * 4 + (w >> 1);    // this wave's last compute tile
  int Nt   = qb * 4 + 4;           // tiles staged by the block

  const bf16* Qp = Q + (((size_t)b * NH + h) * Td) * HD;
  const char* Kg = (const char*)(K + (((size_t)b * NKV + kvh) * Td) * HD);   // rows 128B
  const char* Vg = (const char*)(Vt + (((size_t)b * NKV + kvh) * HD) * Td);  // rows 4096B

  // Q B-fragments (pre-scaled in QKV epilogue): qf[ck][j] = Q[qg][ck*16+H*8+j]
  short8 qf[4];
#pragma unroll
  for (int ck = 0; ck < 4; ++ck)
    qf[ck] = *(const short8*)(Qp + (size_t)qg * HD + ck * 16 + H * 8);

  // staging geometry: wave w stages tile rows [w*8, w*8+8), 16B per lane
  int srow   = lane >> 3;                       // 0..7 within the 8-row slab
  int scol16 = ((lane & 7) ^ srow) << 4;        // inverse-swizzled byte col
  const char* Ksrc0 = Kg + (size_t)(w * 8 + srow) * 128 + scol16;
  const char* Vsrc0 = Vg + (size_t)(w * 8 + srow) * 4096 + scol16;
  char* KldsW[2] = { lds + w * 1024,          lds + 16384 + w * 1024 };
  char* VldsW[2] = { lds + 8192 + w * 1024,   lds + 24576 + w * 1024 };

#define STAGE_KV(tt, bb) do {                                                 \
    GLOAD_LDS16(Ksrc0 + (size_t)(tt) * 64 * 128, KldsW[bb]);                  \
    GLOAD_LDS16(Vsrc0 + (size_t)(tt) * 128,      VldsW[bb]);                  \
  } while (0)

  f32x16 acc0 = {}, acc1 = {};     // O^T[d][q], d 0..31 / 32..63
  float m = -3e38f, l = 0.0f;
  int swz = (lq & 7) << 4;
  int rb0 = lq * 128, rb1 = (32 + lq) * 128;

  STAGE_KV(0, 0);
  asm volatile("s_waitcnt vmcnt(0)" ::: "memory");
  __syncthreads();

  for (int t = 0; t < Nt; ++t) {
    int cur = t & 1;
    if (t + 1 < Nt) STAGE_KV(t + 1, cur ^ 1);
    if (t <= tmax) {
      const char* Kl = lds + cur * 16384;
      const char* Vl = Kl + 8192;
      // ---- S^T = K . Q^T ----
      f32x16 s0 = {}, s1 = {};
      __builtin_amdgcn_s_setprio(1);
#pragma unroll
      for (int ck = 0; ck < 4; ++ck) {
        int c = (H * 16 + ck * 32) ^ swz;
        short8 kf0 = *(const short8*)(Kl + rb0 + c);
        short8 kf1 = *(const short8*)(Kl + rb1 + c);
        s0 = MFMA32(kf0, qf[ck], s0);
        s1 = MFMA32(kf1, qf[ck], s1);
      }
      __builtin_amdgcn_s_setprio(0);
      // ---- causal mask (diagonal tile only) ----
      if (t == tmax) {
        int kvb = t * 64;
#pragma unroll
        for (int rr = 0; rr < 16; ++rr) {
          int krel = (rr & 3) + 8 * (rr >> 2) + 4 * H;
          if (kvb + krel > qg)      s0[rr] = -3e38f;
          if (kvb + 32 + krel > qg) s1[rr] = -3e38f;
        }
      }
      // ---- row max (register tree + cross-half permlane swap) ----
      float mx = fmaxf(hmax16(s0), hmax16(s1));
      {
        float mb = mx;
        asm("" : "+v"(mb));
        plswapf(mx, mb);
        mx = fmaxf(mx, mb);
      }
      // ---- defer-rescale (T13, THR=8 in log2 domain) ----
      if (__any(mx > m + 8.0f)) {
        float mn = fmaxf(m, mx);
        float al = __builtin_amdgcn_exp2f(m - mn);
        m = mn;
        l *= al;
#pragma unroll
        for (int rr = 0; rr < 16; ++rr) { acc0[rr] *= al; acc1[rr] *= al; }
      }
      // ---- p = exp2(s - m) ----
#pragma unroll
      for (int rr = 0; rr < 16; ++rr) {
        s0[rr] = __builtin_amdgcn_exp2f(s0[rr] - m);
        s1[rr] = __builtin_amdgcn_exp2f(s1[rr] - m);
      }
      float ps = hsum16(s0) + hsum16(s1);
      {
        float pb = ps;
        asm("" : "+v"(pb));
        plswapf(ps, pb);
        ps += pb;
      }
      l += ps;
      // ---- pack P -> bf16 B-fragments (T12: cvt_pk + permlane32_swap) ----
      short8 pf[4];
#pragma unroll
      for (int tt = 0; tt < 2; ++tt) {
        const f32x16& sv = tt ? s1 : s0;
#pragma unroll
        for (int a2 = 0; a2 < 2; ++a2) {
          unsigned int A0 = pkbf(sv[8*a2 + 0], sv[8*a2 + 1]);
          unsigned int A1 = pkbf(sv[8*a2 + 2], sv[8*a2 + 3]);
          unsigned int B0 = pkbf(sv[8*a2 + 4], sv[8*a2 + 5]);
          unsigned int B1 = pkbf(sv[8*a2 + 6], sv[8*a2 + 7]);
          plswapu(A0, B0);
          plswapu(A1, B1);
          u32x4 t4;
          t4[0] = A0; t4[1] = A1; t4[2] = B0; t4[3] = B1;
          pf[2*tt + a2] = __builtin_bit_cast(short8, t4);
        }
      }
      // ---- O^T += V^T . P ----
      __builtin_amdgcn_s_setprio(1);
#pragma unroll
      for (int ks = 0; ks < 4; ++ks) {
        int c = (H * 16 + ks * 32) ^ swz;
        short8 vf0 = *(const short8*)(Vl + rb0 + c);
        short8 vf1 = *(const short8*)(Vl + rb1 + c);
        acc0 = MFMA32(vf0, pf[ks], acc0);
        acc1 = MFMA32(vf1, pf[ks], acc1);
      }
      __builtin_amdgcn_s_setprio(0);
    }
    asm volatile("s_waitcnt vmcnt(0)" ::: "memory");
    __syncthreads();
  }
#undef STAGE_KV

  // ---- epilogue: normalize, write Y[M][C] ----
  float rn = 1.0f / l;
  bf16* Yp = Y + ((size_t)b * Td + qg) * Cd + h * HD;
#pragma unroll
  for (int rr = 0; rr < 16; rr += 2) {
    int d = (rr & 3) + 8 * (rr >> 2) + 4 * H;   // d, d+1 for rr, rr+1
    unsigned int w0 = pkbf(acc0[rr] * rn, acc0[rr + 1] * rn);
    unsigned int w1 = pkbf(acc1[rr] * rn, acc1[rr + 1] * rn);
    *(unsigned int*)(Yp + d)      = w0;
    *(unsigned int*)(Yp + 32 + d) = w1;
  }
}

// ---------------------------------------------------------------------------
extern "C" void kernel_launch(void* const* d_in, const int* in_sizes, int n_in,
                              void* d_out, int out_size, void* d_ws, size_t ws_size,
                              hipStream_t stream) {
  const float* x  = (const float*)d_in[0];
  const float* wq = (const float*)d_in[1];
  const float* wk = (const float*)d_in[2];
  const float* wv = (const float*)d_in[3];
  const float* wo = (const float*)d_in[4];

  char* ws = (char*)d_ws;
  const size_t o_xb = 0;                                   // 16.78 MB (reused as yb)
  const size_t o_w1 = o_xb + (size_t)Md * Cd * 2;          // 12.58 MB (wqkvT / later woT)
  const size_t o_Q  = o_w1 + (size_t)3072 * Cd * 2;        // 16.78 MB
  const size_t o_K  = o_Q + (size_t)Bd * NH * Td * HD * 2; // 4.19 MB
  const size_t o_V  = o_K + (size_t)Bd * NKV * Td * HD * 2;// 4.19 MB

  bf16* xb  = (bf16*)(ws + o_xb);
  bf16* w1  = (bf16*)(ws + o_w1);
  bf16* Qb  = (bf16*)(ws + o_Q);
  bf16* Kb  = (bf16*)(ws + o_K);
  bf16* Vtb = (bf16*)(ws + o_V);
  bf16* yb  = xb;   // alias: x_bf16 dead after QKV GEMM

  // 1. prep1: x->bf16 + wq/wk/wv transposes (one launch)
  prep1_kernel<<<dim3(14336), dim3(256), 0, stream>>>(x, wq, wk, wv, xb, w1);
  // 2. fused QKV projection (N = 3072) with in-epilogue RoPE
  gemm_bf16<3><<<dim3(Md / 128, 3072 / 128), dim3(256), 0, stream>>>(xb, w1, Qb, Md, 3072, Cd);
  // 3. wo transpose into w1 (wqkvT dead after QKV GEMM)
  transpose_f2b<<<dim3(Cd / 32, Cd / 32), dim3(256), 0, stream>>>(wo, w1, Cd, Cd);
  // 4. attention -> yb (bf16 [M][C]); 8-wave LDS-staged blocks, LPT order
  attn_kernel<<<dim3(Bd * NH, 8), dim3(512), 0, stream>>>(Qb, Kb, Vtb, yb);
  // 5. output projection -> d_out (fp32)
  gemm_bf16<2><<<dim3(Md / 128, Cd / 128), dim3(256), 0, stream>>>(yb, w1, d_out, Md, Cd, Cd);
}